// Round 15
// baseline (321.041 us; speedup 1.0000x reference)
//
#include <hip/hip_runtime.h>
#include <math.h>

#define CDIM 2048
#define QKVW 6144

typedef __bf16 bf16x8 __attribute__((ext_vector_type(8)));
typedef __bf16 bf16x4 __attribute__((ext_vector_type(4)));
typedef float  f32x4  __attribute__((ext_vector_type(4)));
typedef float  f32x16 __attribute__((ext_vector_type(16)));

__device__ __constant__ float SIGNS_c[64] = {
  1,  1,  1,  1,  1,  1,  1,  1,
  1, -1,  1, -1,  1, -1, -1,  1,
  1, -1, -1,  1,  1,  1, -1, -1,
  1,  1, -1, -1,  1, -1,  1, -1,
  1, -1, -1, -1, -1,  1,  1,  1,
  1,  1, -1,  1, -1, -1, -1,  1,
  1,  1,  1, -1, -1,  1, -1, -1,
  1, -1,  1,  1, -1, -1,  1, -1
};

__device__ __forceinline__ void load_lds16(const void* g, void* lp) {
  __builtin_amdgcn_global_load_lds(
      (const __attribute__((address_space(1))) unsigned int*)g,
      (__attribute__((address_space(3))) unsigned int*)lp, 16, 0, 0);
}

__device__ __forceinline__ void wg_barrier() {
  asm volatile("" ::: "memory");
  __builtin_amdgcn_s_barrier();
  asm volatile("" ::: "memory");
}

__device__ __forceinline__ unsigned pack2(float a, float b) {
  union { __bf16 h[2]; unsigned u; } x;
  x.h[0] = (__bf16)a; x.h[1] = (__bf16)b; return x.u;
}

// ---- fused: cast x -> bf16 (blocks 0..8191) + partial |W| sums (blocks 8192..8447) ----
__global__ __launch_bounds__(256)
void cast_scale(const float* __restrict__ x, __bf16* __restrict__ xb,
                const float* __restrict__ wq, const float* __restrict__ wk,
                const float* __restrict__ wv, const float* __restrict__ wo,
                double* __restrict__ part) {
  __shared__ double red[256];
  if (blockIdx.x < 8192) {
    int i = blockIdx.x * 256 + threadIdx.x;
    float4 v = *(const float4*)(x + (size_t)i * 4);
    bf16x4 o;
    o[0] = (__bf16)v.x; o[1] = (__bf16)v.y; o[2] = (__bf16)v.z; o[3] = (__bf16)v.w;
    *(bf16x4*)(xb + (size_t)i * 4) = o;
    return;
  }
  int bid = blockIdx.x - 8192;
  int which = bid >> 6, m = (bid >> 3) & 7, seg = bid & 7;
  const float* W = (which == 0) ? wq : (which == 1) ? wk : (which == 2) ? wv : wo;
  const float4* w4 = (const float4*)(W + (m << 16) + seg * 8192);
  double acc = 0.0;
  #pragma unroll
  for (int i = 0; i < 8; ++i) {
    float4 v = w4[threadIdx.x + i * 256];
    acc += (double)fabsf(v.x) + (double)fabsf(v.y) +
           (double)fabsf(v.z) + (double)fabsf(v.w);
  }
  red[threadIdx.x] = acc;
  __syncthreads();
  for (int s = 128; s > 0; s >>= 1) {
    if (threadIdx.x < s) red[threadIdx.x] += red[threadIdx.x + s];
    __syncthreads();
  }
  if (threadIdx.x == 0) part[bid] = red[0];
}

// ---- fixed-order final sum + reciprocal (deterministic) ----
__global__ void scale_fin(const double* __restrict__ part, double* __restrict__ s8,
                          double* __restrict__ rs8) {
  int t = threadIdx.x;
  if (t < 32) {
    double a = 0.0;
    #pragma unroll
    for (int i = 0; i < 8; ++i) a += part[t * 8 + i];
    double s = a / 65536.0 + 1e-8;
    s8[t] = s;
    rs8[t] = 1.0 / s;
  }
}

__global__ void build_oct3(const float* __restrict__ wq, const float* __restrict__ wk,
                           const float* __restrict__ wv, const double* __restrict__ s8,
                           const double* __restrict__ rs8, __bf16* __restrict__ MT) {
  int z = blockIdx.y;
  const float* W = (z == 0) ? wq : (z == 1) ? wk : wv;
  const double* sp = s8 + z * 8;
  const double* rp = rs8 + z * 8;
  __bf16* out = MT + (size_t)z * 4194304;
  int idx = blockIdx.x * 256 + threadIdx.x;
  int row = idx & 2047, col = idx >> 11;
  int i = col >> 8, d = col & 255, j = row >> 8, c = row & 255;
  int m = i ^ j;
  double q = rint((double)W[(m << 16) + (c << 8) + d] * rp[m]);
  q = fmin(fmax(q, -1.0), 1.0);
  out[idx] = (__bf16)(SIGNS_c[i * 8 + j] * (float)(q * sp[m]));
}

__global__ void build_oct_T(const float* __restrict__ W, const double* __restrict__ s8,
                            const double* __restrict__ rs8, __bf16* __restrict__ MT) {
  int idx = blockIdx.x * 256 + threadIdx.x;
  int row = idx & 2047, col = idx >> 11;
  int i = col >> 8, d = col & 255, j = row >> 8, c = row & 255;
  int m = i ^ j;
  double q = rint((double)W[(m << 16) + (c << 8) + d] * rs8[m]);
  q = fmin(fmax(q, -1.0), 1.0);
  MT[idx] = (__bf16)(SIGNS_c[i * 8 + j] * (float)(q * s8[m]));
}

// ---- UNtransposed mixer block with beta folded (for Mfused) ----
__global__ void build_mix_plain(const float* __restrict__ Wm, const float* __restrict__ beta,
                                __bf16* __restrict__ M) {
  int idx = blockIdx.x * 256 + threadIdx.x;
  int kl = idx & 1023, kpl = idx >> 10;
  int j = kpl >> 7, dd = kpl & 127;
  int i = kl >> 7, e = kl & 127;
  M[idx] = (__bf16)(SIGNS_c[i * 8 + j] * Wm[((i ^ j) << 14) + (dd << 7) + e] * beta[e]);
}

// ---- 8-phase 256x192 BK=64 GEMM for QKV with fused RoPE epilogue ----
__global__ __launch_bounds__(512, 2)
void gemm_qkv8(const __bf16* __restrict__ A, const __bf16* __restrict__ BT,
               const float* __restrict__ fc, const float* __restrict__ fs,
               __bf16* __restrict__ C) {
  __shared__ __align__(16) char smem[131072];
  int tid = threadIdx.x;
  int w = tid >> 6, l = tid & 63, hi = l >> 4, lo = l & 15;
  int wm = w >> 2, wn = w & 3;
  int lin = blockIdx.x;
  int xcd = lin & 7, idx = lin >> 3;
  int cy = xcd >> 2, cx = xcd & 3;
  int iby = idx >> 3, ibx = idx & 7;
  int bm = (cy * 8 + iby) * 256;
  int bn = (cx * 8 + ibx) * 192;
  const char* Ab = (const char*)A + (size_t)bm * 4096;
  const char* Bb = (const char*)BT + (size_t)bn * 4096;

  int sw = (((lo & 1) << 2) + hi) ^ (lo >> 1);

  int se_r[2], se_g[2], se_rb[2];
  #pragma unroll
  for (int q = 0; q < 2; ++q) {
    int e = q * 512 + tid;
    int lr = e >> 3, sl = e & 7;
    int x = sl ^ (lr & 7);
    se_r[q] = lr * 2 + (x >> 2);
    se_g[q] = x & 3;
    se_rb[q] = se_r[q] < 192 ? se_r[q] : 191;
  }
  int dstoff[2] = { (0 * 512 + w * 64) * 16, (1 * 512 + w * 64) * 16 };

  f32x4 acc[8][3];
  #pragma unroll
  for (int m = 0; m < 8; ++m)
    #pragma unroll
    for (int n = 0; n < 3; ++n) acc[m][n] = (f32x4){0.f, 0.f, 0.f, 0.f};
  bf16x8 bfr[3];

  #define STG(MAT, TT, KH) do {                                                  \
    char* dst_ = smem + ((TT) & 1) * 65536 + (MAT) * 32768 + (KH) * 16384;       \
    const char* gb_ = (MAT) ? Bb : Ab;                                           \
    _Pragma("unroll")                                                            \
    for (int q = 0; q < 2; ++q) {                                                \
      int r_ = (MAT) ? se_rb[q] : se_r[q];                                       \
      load_lds16(gb_ + (size_t)r_ * 4096 + ((TT) * 64 + (KH) * 32) * 2 + se_g[q] * 16, \
                 dst_ + dstoff[q]);                                              \
    }                                                                            \
  } while (0)

  #define QUAD(TT, KH, MSUB, READB) do {                                         \
    const char* ar_ = smem + ((TT) & 1) * 65536 + (KH) * 16384;                  \
    const char* br_ = ar_ + 32768;                                               \
    if (READB) {                                                                 \
      _Pragma("unroll")                                                          \
      for (int n = 0; n < 3; ++n)                                                \
        bfr[n] = *(const bf16x8*)(br_ + (wn * 24 + n * 8 + (lo >> 1)) * 128 + sw * 16); \
    }                                                                            \
    bf16x8 afr[4];                                                               \
    _Pragma("unroll")                                                            \
    for (int m = 0; m < 4; ++m)                                                  \
      afr[m] = *(const bf16x8*)(ar_ + (wm * 64 + (MSUB) * 32 + m * 8 + (lo >> 1)) * 128 + sw * 16); \
    __builtin_amdgcn_s_setprio(1);                                               \
    _Pragma("unroll")                                                            \
    for (int m = 0; m < 4; ++m)                                                  \
      _Pragma("unroll")                                                          \
      for (int n = 0; n < 3; ++n)                                                \
        acc[(MSUB) * 4 + m][n] =                                                 \
            __builtin_amdgcn_mfma_f32_16x16x32_bf16(afr[m], bfr[n], acc[(MSUB) * 4 + m][n], 0, 0, 0); \
    __builtin_amdgcn_s_setprio(0);                                               \
  } while (0)

  #define LGK0() asm volatile("s_waitcnt lgkmcnt(0)" ::: "memory")
  #define VMW8() asm volatile("s_waitcnt vmcnt(8)" ::: "memory")
  #define VMW4() asm volatile("s_waitcnt vmcnt(4)" ::: "memory")
  #define VMW0() asm volatile("s_waitcnt vmcnt(0)" ::: "memory")

  STG(0, 0, 0); STG(1, 0, 0);
  STG(0, 0, 1); STG(1, 0, 1);
  STG(0, 1, 0); STG(1, 1, 0);
  VMW8();
  wg_barrier();

  #define GITER(T0, LAST) do {                                                   \
    /* ph1 */ STG(0, (T0) + 1, 1); QUAD((T0), 0, 0, 1); wg_barrier();            \
    /* ph2 */ STG(1, (T0) + 1, 1); QUAD((T0), 0, 1, 0); LGK0(); VMW8(); wg_barrier(); \
    /* ph3 */ if (!(LAST)) { STG(0, (T0) + 2, 0); } QUAD((T0), 1, 0, 1); wg_barrier(); \
    /* ph4 */ if (!(LAST)) { STG(1, (T0) + 2, 0); } QUAD((T0), 1, 1, 0); LGK0(); \
              if (LAST) { VMW4(); } else { VMW8(); } wg_barrier();               \
    /* ph5 */ if (!(LAST)) { STG(0, (T0) + 2, 1); } QUAD((T0) + 1, 0, 0, 1); wg_barrier(); \
    /* ph6 */ if (!(LAST)) { STG(1, (T0) + 2, 1); } QUAD((T0) + 1, 0, 1, 0); LGK0(); \
              if (LAST) { VMW0(); } else { VMW8(); } wg_barrier();               \
    /* ph7 */ if (!(LAST)) { STG(0, (T0) + 3, 0); } QUAD((T0) + 1, 1, 0, 1); wg_barrier(); \
    /* ph8 */ if (!(LAST)) { STG(1, (T0) + 3, 0); } QUAD((T0) + 1, 1, 1, 0);     \
              if (!(LAST)) { LGK0(); VMW8(); wg_barrier(); }                     \
  } while (0)

  for (int i = 0; i < 15; ++i) GITER(2 * i, false);
  GITER(30, true);

  #undef GITER
  #undef STG
  #undef QUAD
  #undef VMW8
  #undef VMW4
  #undef LGK0
  #undef VMW0

  // epilogue with fused RoPE on Q/K columns (col<4096); even/odd pair via shfl_xor(1)
  #pragma unroll
  for (int mm = 0; mm < 8; ++mm)
    #pragma unroll
    for (int n = 0; n < 3; ++n) {
      int col = bn + wn * 48 + n * 16 + lo;
      int isqk = (col < 4096);              // wave-uniform (16-aligned group)
      int p = (col & 127) >> 1;
      int evenl = ((col & 1) == 0);
      #pragma unroll
      for (int r = 0; r < 4; ++r) {
        int row = bm + wm * 128 + mm * 16 + hi * 4 + r;
        float v = acc[mm][n][r];
        float other = __shfl_xor(v, 1, 64);  // all lanes execute
        if (isqk) {
          int t = row & 1023;
          float c = fc[t * 64 + p];
          float s = fs[t * 64 + p];
          v = evenl ? (v * c - other * s) : (other * s + v * c);
        }
        C[(size_t)row * QKVW + col] = (__bf16)v;
      }
    }
}

// ---- 8-phase final GEMM: out = Aq(Q cols, lda 6144) @ BTfused^T (R14-proven) ----
__global__ __launch_bounds__(512, 2)
void gemm_fin8(const __bf16* __restrict__ A, const __bf16* __restrict__ BT,
               float* __restrict__ C) {
  __shared__ __align__(16) char smem[98304];
  int tid = threadIdx.x;
  int w = tid >> 6, l = tid & 63, hi = l >> 4, lo = l & 15;
  int wm = w >> 2, wn = w & 3;
  int lin = blockIdx.x;
  int xcd = lin & 7, idx = lin >> 3;
  int cy = xcd >> 1, cx = xcd & 1;
  int iby = idx >> 2, ibx = idx & 3;
  int bm = (cy * 8 + iby) * 128;
  int bn = (cx * 4 + ibx) * 256;
  const char* Ab = (const char*)A + (size_t)bm * 12288;
  const char* Bb = (const char*)BT + (size_t)bn * 4096;

  int sw = (((lo & 1) << 2) + hi) ^ (lo >> 1);

  int se_r[2], se_g[2];
  #pragma unroll
  for (int q = 0; q < 2; ++q) {
    int e = q * 512 + tid;
    int lr = e >> 3, sl = e & 7;
    int x = sl ^ (lr & 7);
    se_r[q] = lr * 2 + (x >> 2);
    se_g[q] = x & 3;
  }
  int dstoff[2] = { (0 * 512 + w * 64) * 16, (1 * 512 + w * 64) * 16 };

  f32x4 acc[4][4];
  #pragma unroll
  for (int m = 0; m < 4; ++m)
    #pragma unroll
    for (int n = 0; n < 4; ++n) acc[m][n] = (f32x4){0.f, 0.f, 0.f, 0.f};
  bf16x8 bfr[4];

  #define STG(MAT, TT, KH) do {                                                  \
    char* ab_ = smem + ((TT) & 1) * 49152;                                       \
    char* dst_ = (MAT) ? (ab_ + 16384 + (KH) * 16384) : (ab_ + (KH) * 8192);     \
    const char* gb_ = (MAT) ? Bb : Ab;                                           \
    size_t ld_ = (MAT) ? 4096 : 12288;                                           \
    int nq_ = (MAT) ? 2 : 1;                                                     \
    _Pragma("unroll")                                                            \
    for (int q = 0; q < 2; ++q)                                                  \
      if (q < nq_)                                                               \
        load_lds16(gb_ + (size_t)se_r[q] * ld_ + ((TT) * 64 + (KH) * 32) * 2 + se_g[q] * 16, \
                   dst_ + dstoff[q]);                                            \
  } while (0)

  #define QUAD(TT, KH, MSUB, READB) do {                                         \
    const char* ab_ = smem + ((TT) & 1) * 49152;                                 \
    const char* ar_ = ab_ + (KH) * 8192;                                         \
    const char* br_ = ab_ + 16384 + (KH) * 16384;                                \
    if (READB) {                                                                 \
      _Pragma("unroll")                                                          \
      for (int n = 0; n < 4; ++n)                                                \
        bfr[n] = *(const bf16x8*)(br_ + (wn * 32 + n * 8 + (lo >> 1)) * 128 + sw * 16); \
    }                                                                            \
    bf16x8 afr[2];                                                               \
    _Pragma("unroll")                                                            \
    for (int m = 0; m < 2; ++m)                                                  \
      afr[m] = *(const bf16x8*)(ar_ + (wm * 32 + (MSUB) * 16 + m * 8 + (lo >> 1)) * 128 + sw * 16); \
    __builtin_amdgcn_s_setprio(1);                                               \
    _Pragma("unroll")                                                            \
    for (int m = 0; m < 2; ++m)                                                  \
      _Pragma("unroll")                                                          \
      for (int n = 0; n < 4; ++n)                                                \
        acc[(MSUB) * 2 + m][n] =                                                 \
            __builtin_amdgcn_mfma_f32_16x16x32_bf16(afr[m], bfr[n], acc[(MSUB) * 2 + m][n], 0, 0, 0); \
    __builtin_amdgcn_s_setprio(0);                                               \
  } while (0)

  #define LGK0() asm volatile("s_waitcnt lgkmcnt(0)" ::: "memory")
  #define VMW6() asm volatile("s_waitcnt vmcnt(6)" ::: "memory")
  #define VMW3() asm volatile("s_waitcnt vmcnt(3)" ::: "memory")
  #define VMW0() asm volatile("s_waitcnt vmcnt(0)" ::: "memory")

  STG(0, 0, 0); STG(1, 0, 0);
  STG(0, 0, 1); STG(1, 0, 1);
  STG(0, 1, 0); STG(1, 1, 0);
  VMW6();
  wg_barrier();

  #define GITER(T0, LAST) do {                                                   \
    /* ph1 */ STG(0, (T0) + 1, 1); QUAD((T0), 0, 0, 1); wg_barrier();            \
    /* ph2 */ STG(1, (T0) + 1, 1); QUAD((T0), 0, 1, 0); LGK0(); VMW6(); wg_barrier(); \
    /* ph3 */ if (!(LAST)) { STG(0, (T0) + 2, 0); } QUAD((T0), 1, 0, 1); wg_barrier(); \
    /* ph4 */ if (!(LAST)) { STG(1, (T0) + 2, 0); } QUAD((T0), 1, 1, 0); LGK0(); \
              if (LAST) { VMW3(); } else { VMW6(); } wg_barrier();               \
    /* ph5 */ if (!(LAST)) { STG(0, (T0) + 2, 1); } QUAD((T0) + 1, 0, 0, 1); wg_barrier(); \
    /* ph6 */ if (!(LAST)) { STG(1, (T0) + 2, 1); } QUAD((T0) + 1, 0, 1, 0); LGK0(); \
              if (LAST) { VMW0(); } else { VMW6(); } wg_barrier();               \
    /* ph7 */ if (!(LAST)) { STG(0, (T0) + 3, 0); } QUAD((T0) + 1, 1, 0, 1); wg_barrier(); \
    /* ph8 */ if (!(LAST)) { STG(1, (T0) + 3, 0); } QUAD((T0) + 1, 1, 1, 0);     \
              if (!(LAST)) { LGK0(); VMW6(); wg_barrier(); }                     \
  } while (0)

  for (int i = 0; i < 15; ++i) GITER(2 * i, false);
  GITER(30, true);

  #undef GITER
  #undef STG
  #undef QUAD
  #undef VMW6
  #undef VMW3
  #undef LGK0
  #undef VMW0

  #pragma unroll
  for (int mm = 0; mm < 4; ++mm)
    #pragma unroll
    for (int n = 0; n < 4; ++n)
      #pragma unroll
      for (int r = 0; r < 4; ++r) {
        int row = bm + wm * 64 + mm * 16 + hi * 4 + r;
        int col = bn + wn * 64 + n * 16 + lo;
        C[(size_t)row * 2048 + col] = acc[mm][n][r];
      }
}

// ---- phase-split counted-vmcnt GEMM (2-phase, for Mfused prep) ----
template<int BN, int NBY, int NBX, int CBY, int CBX, int KLEN, int LDA, int OUT_BF16>
__global__ __launch_bounds__(512, 2)
void gemm_ps(const __bf16* __restrict__ A, const __bf16* __restrict__ BT,
             void* __restrict__ Cout, int az, int cz, int ldc) {
  constexpr int FN = BN / 64;
  constexpr int LB = (BN > 128) ? 2 : 1;
  constexpr int VC = 2 + LB;
  constexpr int BUFSZ = 16384 + 8192 * LB;
  constexpr int CGX = NBX / CBX;
  static_assert((NBY / CBY) * CGX == 8, "chunk grid must be 8 XCDs");
  __shared__ __align__(16) char smem[2 * BUFSZ];
  int tid = threadIdx.x;
  int w = tid >> 6, l = tid & 63, hi = l >> 4, lo = l & 15;
  int wm = w >> 2, wn = w & 3;
  int lin = blockIdx.x;
  int xcd = lin & 7, idx = lin >> 3;
  int cy = xcd / CGX, cx = xcd % CGX;
  int iby = idx / CBX, ibx = idx % CBX;
  int bm = (cy * CBY + iby) * 256;
  int bn = (cx * CBX + ibx) * BN;
  const char* Ab = (const char*)(A + (size_t)blockIdx.y * az) + (size_t)bm * LDA * 2;
  const char* Bb = (const char*)BT + (size_t)bn * KLEN * 2;

  int sw = (((lo & 1) << 2) + hi) ^ (lo >> 1);
  int base_a = (wm * 64 + (lo >> 1)) * 128 + sw * 16;
  int base_b = 16384 + (wn * (BN / 8) + (lo >> 1)) * 128 + sw * 16;

  int se_r[2], se_g[2];
  #pragma unroll
  for (int q = 0; q < 2; ++q) {
    int e = q * 512 + tid;
    int lr = e >> 3, sl = e & 7;
    int x = sl ^ (lr & 7);
    se_r[q] = lr * 2 + (x >> 2);
    se_g[q] = x & 3;
  }
  int dstoff[2] = { (0 * 512 + w * 64) * 16, (1 * 512 + w * 64) * 16 };

  f32x4 acc[8][FN];
  #pragma unroll
  for (int m = 0; m < 8; ++m)
    #pragma unroll
    for (int n = 0; n < FN; ++n) acc[m][n] = (f32x4){0.f, 0.f, 0.f, 0.f};

  #define STAGE(BUFI, K0) do {                                                   \
    char* As_ = smem + (BUFI) * BUFSZ;                                           \
    char* Bs_ = As_ + 16384;                                                     \
    _Pragma("unroll")                                                            \
    for (int q = 0; q < 2; ++q)                                                  \
      load_lds16(Ab + (size_t)se_r[q] * (LDA * 2) + (size_t)(K0) * 2 + se_g[q] * 16, \
                 As_ + dstoff[q]);                                               \
    _Pragma("unroll")                                                            \
    for (int q = 0; q < LB; ++q)                                                 \
      load_lds16(Bb + (size_t)se_r[q] * (KLEN * 2) + (size_t)(K0) * 2 + se_g[q] * 16, \
                 Bs_ + dstoff[q]);                                               \
  } while (0)

  #define WAITVC() do {                                                \
    if constexpr (VC == 4) asm volatile("s_waitcnt vmcnt(4)" ::: "memory"); \
    else                   asm volatile("s_waitcnt vmcnt(3)" ::: "memory"); \
  } while (0)

  constexpr int NT = KLEN / 32;
  STAGE(0, 0);
  STAGE(1, 32);
  WAITVC();
  wg_barrier();

  for (int t = 0; t < NT; ++t) {
    char* buf = smem + (t & 1) * BUFSZ;
    bf16x8 bfr[FN], afr[8];
    #pragma unroll
    for (int n = 0; n < FN; ++n) bfr[n] = *(const bf16x8*)(buf + base_b + n * 1024);
    #pragma unroll
    for (int m = 0; m < 8; ++m) afr[m] = *(const bf16x8*)(buf + base_a + m * 1024);
    __builtin_amdgcn_s_setprio(1);
    #pragma unroll
    for (int m = 0; m < 4; ++m)
      #pragma unroll
      for (int n = 0; n < FN; ++n)
        acc[m][n] = __builtin_amdgcn_mfma_f32_16x16x32_bf16(afr[m], bfr[n], acc[m][n], 0, 0, 0);
    __builtin_amdgcn_s_setprio(0);
    asm volatile("s_waitcnt lgkmcnt(0)" ::: "memory");
    wg_barrier();

    if (t + 2 < NT) STAGE(t & 1, (t + 2) * 32);
    __builtin_amdgcn_s_setprio(1);
    #pragma unroll
    for (int m = 4; m < 8; ++m)
      #pragma unroll
      for (int n = 0; n < FN; ++n)
        acc[m][n] = __builtin_amdgcn_mfma_f32_16x16x32_bf16(afr[m], bfr[n], acc[m][n], 0, 0, 0);
    __builtin_amdgcn_s_setprio(0);
    if (t + 2 < NT) { WAITVC(); }
    else            { asm volatile("s_waitcnt vmcnt(0)" ::: "memory"); }
    wg_barrier();
  }
  #undef STAGE
  #undef WAITVC

  #pragma unroll
  for (int m = 0; m < 8; ++m)
    #pragma unroll
    for (int n = 0; n < FN; ++n)
      #pragma unroll
      for (int r = 0; r < 4; ++r) {
        int row = bm + wm * 128 + m * 16 + hi * 4 + r;
        int col = bn + wn * (BN / 4) + n * 16 + lo;
        if (OUT_BF16)
          ((__bf16*)Cout)[(size_t)blockIdx.y * cz + (size_t)row * ldc + col] = (__bf16)acc[m][n][r];
        else
          ((float*)Cout)[(size_t)blockIdx.y * cz + (size_t)row * ldc + col] = acc[m][n][r];
      }
}

// ---- transpose V cols of QKV -> VT[(bh*128+d)][t] ----
__global__ __launch_bounds__(256)
void transpose_v(const __bf16* __restrict__ QKV, __bf16* __restrict__ VT) {
  __shared__ __bf16 tile[64][136];
  int tid = threadIdx.x;
  int tt = blockIdx.x;
  int bh = blockIdx.y;
  int b = bh >> 4, h = bh & 15;
  int t0 = tt * 64;
  #pragma unroll
  for (int q = 0; q < 4; ++q) {
    int i = q * 256 + tid;
    int tr = i >> 4, u = i & 15;
    bf16x8 v = *(const bf16x8*)(QKV + (size_t)(b * 1024 + t0 + tr) * QKVW + 4096 + h * 128 + u * 8);
    *(bf16x8*)&tile[tr][u * 8] = v;
  }
  __syncthreads();
  #pragma unroll
  for (int q = 0; q < 4; ++q) {
    int i = q * 256 + tid;
    int d = i >> 3, tu = i & 7;
    bf16x8 o;
    #pragma unroll
    for (int jj = 0; jj < 8; ++jj) o[jj] = tile[tu * 8 + jj][d];
    *(bf16x8*)(VT + ((size_t)bh * 128 + d) * 1024 + t0 + tu * 8) = o;
  }
}

// ---- 32x32 MFMA flash attention, causal, dbuf async staging ----
__global__ __launch_bounds__(256, 2)
void attn_mfma2(__bf16* __restrict__ QKV, const __bf16* __restrict__ VT) {
  __shared__ __align__(16) char smem[65536];
  int tid = threadIdx.x;
  int w = tid >> 6, l = tid & 63;
  int lo = l & 31, hv = l >> 5;
  int wgid = blockIdx.x;
  int xcd = wgid & 7, idx = wgid >> 3;
  int s = idx & 7, j = s >> 1, odd = s & 1, hi5 = idx >> 5;
  int base = hi5 ? 7 - j : j;
  int qt = odd ? 7 - base : base;
  int bh = xcd * 8 + (idx >> 3);
  int b = bh >> 4, h = bh & 15;
  int qb = qt * 128;
  int wq0 = qb + w * 32;
  int qrow = wq0 + lo;
  const __bf16* qp = QKV + (size_t)(b * 1024 + qrow) * QKVW + h * 128;
  bf16x8 qf[8];
  #pragma unroll
  for (int c = 0; c < 8; ++c) qf[c] = *(const bf16x8*)(qp + c * 16 + hv * 8);

  f32x16 o[4];
  #pragma unroll
  for (int n = 0; n < 4; ++n)
    #pragma unroll
    for (int r = 0; r < 16; ++r) o[n][r] = 0.f;
  float mrun = -1e30f, lrun = 0.f;
  const float SCL = 0.08838834764831845f * 1.4426950408889634f;
  int src0 = lo, src1 = 32 + lo;
  int nt = 2 * qt + 2;

  #define ASTAGE(BUF, KT) do {                                                   \
    _Pragma("unroll")                                                            \
    for (int i = 0; i < 4; ++i) {                                                \
      int e = i * 256 + tid;                                                     \
      int row = e >> 4, g = e & 15;                                              \
      int gs = g ^ (row & 7);                                                    \
      const char* src = (const char*)QKV +                                       \
          ((size_t)(b * 1024 + (KT) * 64 + row) * QKVW + 2048 + h * 128) * 2 + gs * 16; \
      load_lds16(src, smem + (BUF) * 16384 + (i * 256 + w * 64) * 16);           \
    }                                                                            \
    _Pragma("unroll")                                                            \
    for (int i = 0; i < 4; ++i) {                                                \
      int e = i * 256 + tid;                                                     \
      int row = e >> 3, g = e & 7;                                               \
      int gs = g ^ (row & 7);                                                    \
      const char* src = (const char*)VT +                                        \
          ((size_t)(bh * 128 + row) * 1024 + (KT) * 64) * 2 + gs * 16;           \
      load_lds16(src, smem + 32768 + (BUF) * 16384 + (i * 256 + w * 64) * 16);   \
    }                                                                            \
  } while (0)

  ASTAGE(0, 0);
  asm volatile("s_waitcnt vmcnt(0)" ::: "memory");
  wg_barrier();

  for (int kt = 0; kt < nt; ++kt) {
    int cur = kt & 1;
    if (kt + 1 < nt) ASTAGE(cur ^ 1, kt + 1);
    int k0 = kt * 64;
    char* Ks  = smem + cur * 16384;
    char* VTs = smem + 32768 + cur * 16384;

    if (k0 <= wq0 + 31) {
      f32x16 sT[2];
      #pragma unroll
      for (int kk = 0; kk < 2; ++kk) {
        #pragma unroll
        for (int r = 0; r < 16; ++r) sT[kk][r] = 0.f;
        #pragma unroll
        for (int c = 0; c < 8; ++c) {
          bf16x8 kf = *(const bf16x8*)(Ks + (kk * 32 + lo) * 256 + (((2 * c + hv) ^ (lo & 7)) * 16));
          sT[kk] = __builtin_amdgcn_mfma_f32_32x32x16_bf16(kf, qf[c], sT[kk], 0, 0, 0);
        }
      }
      bool diag = (k0 + 63 > wq0);
      float pv[2][16];
      #pragma unroll
      for (int kk = 0; kk < 2; ++kk)
        #pragma unroll
        for (int r = 0; r < 16; ++r) {
          float v = sT[kk][r] * SCL;
          if (diag) {
            int kg = k0 + kk * 32 + (r & 3) + 8 * (r >> 2) + 4 * hv;
            if (kg > qrow) v = -1e30f;
          }
          pv[kk][r] = v;
        }
      float mx = pv[0][0];
      #pragma unroll
      for (int kk = 0; kk < 2; ++kk)
        #pragma unroll
        for (int r = 0; r < 16; ++r) mx = fmaxf(mx, pv[kk][r]);
      mx = fmaxf(mx, __shfl_xor(mx, 32, 64));
      if (!__all(mx <= mrun + 8.f)) {
        float mnew = fmaxf(mrun, mx);
        float fac = exp2f(mrun - mnew);
        lrun *= fac;
        #pragma unroll
        for (int n = 0; n < 4; ++n)
          #pragma unroll
          for (int r = 0; r < 16; ++r) o[n][r] *= fac;
        mrun = mnew;
      }
      float rs = 0.f;
      #pragma unroll
      for (int kk = 0; kk < 2; ++kk)
        #pragma unroll
        for (int r = 0; r < 16; ++r) {
          float p = exp2f(pv[kk][r] - mrun);
          pv[kk][r] = p;
          rs += p;
        }
      rs += __shfl_xor(rs, 32, 64);
      lrun += rs;

      unsigned pk[2][4][2];
      #pragma unroll
      for (int kk = 0; kk < 2; ++kk)
        #pragma unroll
        for (int m = 0; m < 4; ++m)
          #pragma unroll
          for (int u = 0; u < 2; ++u)
            pk[kk][m][u] = pack2(pv[kk][m * 4 + 2 * u], pv[kk][m * 4 + 2 * u + 1]);

      #pragma unroll
      for (int kk = 0; kk < 2; ++kk) {
        #pragma unroll
        for (int s2 = 0; s2 < 2; ++s2) {
          unsigned a0 = __shfl(pk[kk][2 * s2][0], src0, 64);
          unsigned b0 = __shfl(pk[kk][2 * s2 + 1][0], src0, 64);
          unsigned a1 = __shfl(pk[kk][2 * s2][1], src0, 64);
          unsigned b1 = __shfl(pk[kk][2 * s2 + 1][1], src0, 64);
          unsigned a2 = __shfl(pk[kk][2 * s2][0], src1, 64);
          unsigned b2 = __shfl(pk[kk][2 * s2 + 1][0], src1, 64);
          unsigned a3 = __shfl(pk[kk][2 * s2][1], src1, 64);
          unsigned b3 = __shfl(pk[kk][2 * s2 + 1][1], src1, 64);
          union { unsigned u[4]; bf16x8 v; } pb;
          pb.u[0] = hv ? b0 : a0;
          pb.u[1] = hv ? b1 : a1;
          pb.u[2] = hv ? b2 : a2;
          pb.u[3] = hv ? b3 : a3;
          int ks16 = 2 * kk + s2;
          #pragma unroll
          for (int n = 0; n < 4; ++n) {
            bf16x8 vf = *(const bf16x8*)(VTs + (n * 32 + lo) * 128 +
                                         (((2 * ks16 + hv) ^ (lo & 7)) * 16));
            o[n] = __builtin_amdgcn_mfma_f32_32x32x16_bf16(vf, pb.v, o[n], 0, 0, 0);
          }
        }
      }
    }
    asm volatile("s_waitcnt vmcnt(0)" ::: "memory");
    wg_barrier();
  }
  #undef ASTAGE

  float inv = 1.f / lrun;
  __bf16* op = QKV + (size_t)(b * 1024 + qrow) * QKVW + h * 128;
  #pragma unroll
  for (int n = 0; n < 4; ++n)
    #pragma unroll
    for (int m4 = 0; m4 < 4; ++m4) {
      bf16x4 ov;
      #pragma unroll
      for (int jj = 0; jj < 4; ++jj) ov[jj] = (__bf16)(o[n][m4 * 4 + jj] * inv);
      *(bf16x4*)(op + n * 32 + 8 * m4 + 4 * hv) = ov;
    }
}

extern "C" void kernel_launch(void* const* d_in, const int* in_sizes, int n_in,
                              void* d_out, int out_size, void* d_ws, size_t ws_size,
                              hipStream_t stream) {
  const float* x    = (const float*)d_in[0];
  const float* fc   = (const float*)d_in[1];
  const float* fs   = (const float*)d_in[2];
  const float* wq   = (const float*)d_in[3];
  const float* wk   = (const float*)d_in[4];
  const float* wv   = (const float*)d_in[5];
  const float* wo   = (const float*)d_in[6];
  const float* wm   = (const float*)d_in[7];
  const float* beta = (const float*)d_in[8];

  char* wsb = (char*)d_ws;
  __bf16* xb      = (__bf16*)(wsb);
  __bf16* MTqkv   = (__bf16*)(wsb + 16777216L);
  __bf16* QKV     = (__bf16*)(wsb + 41943040L);
  __bf16* VTb     = (__bf16*)(wsb + 92274688L);
  double* s8      = (double*)(wsb + 109051904L);   // 32 doubles
  double* part    = (double*)(wsb + 109052160L);   // 256 doubles
  double* rs8     = (double*)(wsb + 109054208L);   // 32 doubles
  __bf16* MTwo    = (__bf16*)(wsb);
  __bf16* BTfused = (__bf16*)(wsb + 8388608L);
  __bf16* MTmixP  = MTqkv;

  dim3 blk(256);

  cast_scale<<<8448, blk, 0, stream>>>(x, xb, wq, wk, wv, wo, part);
  scale_fin<<<1, dim3(64), 0, stream>>>(part, s8, rs8);
  build_oct3<<<dim3(16384, 3), blk, 0, stream>>>(wq, wk, wv, s8, rs8, MTqkv);

  // QKV = xb @ [Mq|Mk|Mv]^T with RoPE fused into the epilogue
  gemm_qkv8<<<512, dim3(512), 0, stream>>>(xb, MTqkv, fc, fs, QKV);

  // fold mixer into final weight: BTfused[c][k'] = sum_k MoT[c][k] * M[k'][k]
  build_oct_T<<<16384, blk, 0, stream>>>(wo, s8 + 24, rs8 + 24, MTwo);
  build_mix_plain<<<4096, blk, 0, stream>>>(wm, beta, MTmixP);
  gemm_ps<128, 8, 8, 2, 4, 1024, 2048, 1>
      <<<dim3(64, 2), dim3(512), 0, stream>>>(MTwo, MTmixP, BTfused, 1024, 1024, 2048);

  transpose_v<<<dim3(16, 64), blk, 0, stream>>>(QKV, VTb);

  attn_mfma2<<<dim3(512), blk, 0, stream>>>(QKV, VTb);

  // out = attn_out @ Mfused (8-phase final GEMM)
  gemm_fin8<<<256, dim3(512), 0, stream>>>(QKV, BTfused, (float*)d_out);
}

// Round 16
// 303.570 us; speedup vs baseline: 1.0576x; 1.0576x over previous
//
#include <hip/hip_runtime.h>
#include <math.h>

#define CDIM 2048
#define QKVW 6144

typedef __bf16 bf16x8 __attribute__((ext_vector_type(8)));
typedef __bf16 bf16x4 __attribute__((ext_vector_type(4)));
typedef float  f32x4  __attribute__((ext_vector_type(4)));
typedef float  f32x16 __attribute__((ext_vector_type(16)));

__device__ __constant__ float SIGNS_c[64] = {
  1,  1,  1,  1,  1,  1,  1,  1,
  1, -1,  1, -1,  1, -1, -1,  1,
  1, -1, -1,  1,  1,  1, -1, -1,
  1,  1, -1, -1,  1, -1,  1, -1,
  1, -1, -1, -1, -1,  1,  1,  1,
  1,  1, -1,  1, -1, -1, -1,  1,
  1,  1,  1, -1, -1,  1, -1, -1,
  1, -1,  1,  1, -1, -1,  1, -1
};

__device__ __forceinline__ void load_lds16(const void* g, void* lp) {
  __builtin_amdgcn_global_load_lds(
      (const __attribute__((address_space(1))) unsigned int*)g,
      (__attribute__((address_space(3))) unsigned int*)lp, 16, 0, 0);
}

__device__ __forceinline__ void wg_barrier() {
  asm volatile("" ::: "memory");
  __builtin_amdgcn_s_barrier();
  asm volatile("" ::: "memory");
}

__device__ __forceinline__ unsigned pack2(float a, float b) {
  union { __bf16 h[2]; unsigned u; } x;
  x.h[0] = (__bf16)a; x.h[1] = (__bf16)b; return x.u;
}

// ---- fused: cast x -> bf16 (blocks 0..8191) + partial |W| sums (blocks 8192..8447) ----
__global__ __launch_bounds__(256)
void cast_scale(const float* __restrict__ x, __bf16* __restrict__ xb,
                const float* __restrict__ wq, const float* __restrict__ wk,
                const float* __restrict__ wv, const float* __restrict__ wo,
                double* __restrict__ part) {
  __shared__ double red[256];
  if (blockIdx.x < 8192) {
    int i = blockIdx.x * 256 + threadIdx.x;
    float4 v = *(const float4*)(x + (size_t)i * 4);
    bf16x4 o;
    o[0] = (__bf16)v.x; o[1] = (__bf16)v.y; o[2] = (__bf16)v.z; o[3] = (__bf16)v.w;
    *(bf16x4*)(xb + (size_t)i * 4) = o;
    return;
  }
  int bid = blockIdx.x - 8192;
  int which = bid >> 6, m = (bid >> 3) & 7, seg = bid & 7;
  const float* W = (which == 0) ? wq : (which == 1) ? wk : (which == 2) ? wv : wo;
  const float4* w4 = (const float4*)(W + (m << 16) + seg * 8192);
  double acc = 0.0;
  #pragma unroll
  for (int i = 0; i < 8; ++i) {
    float4 v = w4[threadIdx.x + i * 256];
    acc += (double)fabsf(v.x) + (double)fabsf(v.y) +
           (double)fabsf(v.z) + (double)fabsf(v.w);
  }
  red[threadIdx.x] = acc;
  __syncthreads();
  for (int s = 128; s > 0; s >>= 1) {
    if (threadIdx.x < s) red[threadIdx.x] += red[threadIdx.x + s];
    __syncthreads();
  }
  if (threadIdx.x == 0) part[bid] = red[0];
}

// ---- fixed-order final sum + reciprocal (deterministic) ----
__global__ void scale_fin(const double* __restrict__ part, double* __restrict__ s8,
                          double* __restrict__ rs8) {
  int t = threadIdx.x;
  if (t < 32) {
    double a = 0.0;
    #pragma unroll
    for (int i = 0; i < 8; ++i) a += part[t * 8 + i];
    double s = a / 65536.0 + 1e-8;
    s8[t] = s;
    rs8[t] = 1.0 / s;
  }
}

__global__ void build_oct3(const float* __restrict__ wq, const float* __restrict__ wk,
                           const float* __restrict__ wv, const double* __restrict__ s8,
                           const double* __restrict__ rs8, __bf16* __restrict__ MT) {
  int z = blockIdx.y;
  const float* W = (z == 0) ? wq : (z == 1) ? wk : wv;
  const double* sp = s8 + z * 8;
  const double* rp = rs8 + z * 8;
  __bf16* out = MT + (size_t)z * 4194304;
  int idx = blockIdx.x * 256 + threadIdx.x;
  int row = idx & 2047, col = idx >> 11;
  int i = col >> 8, d = col & 255, j = row >> 8, c = row & 255;
  int m = i ^ j;
  double q = rint((double)W[(m << 16) + (c << 8) + d] * rp[m]);
  q = fmin(fmax(q, -1.0), 1.0);
  out[idx] = (__bf16)(SIGNS_c[i * 8 + j] * (float)(q * sp[m]));
}

// ---- fused: MoT build (blocks 0..16383) + mixer plain build (16384..20479) ----
__global__ void build_wo_mix(const float* __restrict__ W, const double* __restrict__ s8,
                             const double* __restrict__ rs8, __bf16* __restrict__ MT,
                             const float* __restrict__ Wm, const float* __restrict__ beta,
                             __bf16* __restrict__ Mmix) {
  if (blockIdx.x < 16384) {
    int idx = blockIdx.x * 256 + threadIdx.x;
    int row = idx & 2047, col = idx >> 11;
    int i = col >> 8, d = col & 255, j = row >> 8, c = row & 255;
    int m = i ^ j;
    double q = rint((double)W[(m << 16) + (c << 8) + d] * rs8[m]);
    q = fmin(fmax(q, -1.0), 1.0);
    MT[idx] = (__bf16)(SIGNS_c[i * 8 + j] * (float)(q * s8[m]));
    return;
  }
  int idx = (blockIdx.x - 16384) * 256 + threadIdx.x;
  int kl = idx & 1023, kpl = idx >> 10;
  int j = kpl >> 7, dd = kpl & 127;
  int i = kl >> 7, e = kl & 127;
  Mmix[idx] = (__bf16)(SIGNS_c[i * 8 + j] * Wm[((i ^ j) << 14) + (dd << 7) + e] * beta[e]);
}

// ---- 8-phase 256x192 BK=64 GEMM for QKV (proven R12/R14 config) ----
__global__ __launch_bounds__(512, 2)
void gemm_qkv8(const __bf16* __restrict__ A, const __bf16* __restrict__ BT,
               __bf16* __restrict__ C) {
  __shared__ __align__(16) char smem[131072];
  int tid = threadIdx.x;
  int w = tid >> 6, l = tid & 63, hi = l >> 4, lo = l & 15;
  int wm = w >> 2, wn = w & 3;
  int lin = blockIdx.x;
  int xcd = lin & 7, idx = lin >> 3;
  int cy = xcd >> 2, cx = xcd & 3;
  int iby = idx >> 3, ibx = idx & 7;
  int bm = (cy * 8 + iby) * 256;
  int bn = (cx * 8 + ibx) * 192;
  const char* Ab = (const char*)A + (size_t)bm * 4096;
  const char* Bb = (const char*)BT + (size_t)bn * 4096;

  int sw = (((lo & 1) << 2) + hi) ^ (lo >> 1);

  int se_r[2], se_g[2], se_rb[2];
  #pragma unroll
  for (int q = 0; q < 2; ++q) {
    int e = q * 512 + tid;
    int lr = e >> 3, sl = e & 7;
    int x = sl ^ (lr & 7);
    se_r[q] = lr * 2 + (x >> 2);
    se_g[q] = x & 3;
    se_rb[q] = se_r[q] < 192 ? se_r[q] : 191;
  }
  int dstoff[2] = { (0 * 512 + w * 64) * 16, (1 * 512 + w * 64) * 16 };

  f32x4 acc[8][3];
  #pragma unroll
  for (int m = 0; m < 8; ++m)
    #pragma unroll
    for (int n = 0; n < 3; ++n) acc[m][n] = (f32x4){0.f, 0.f, 0.f, 0.f};
  bf16x8 bfr[3];

  #define STG(MAT, TT, KH) do {                                                  \
    char* dst_ = smem + ((TT) & 1) * 65536 + (MAT) * 32768 + (KH) * 16384;       \
    const char* gb_ = (MAT) ? Bb : Ab;                                           \
    _Pragma("unroll")                                                            \
    for (int q = 0; q < 2; ++q) {                                                \
      int r_ = (MAT) ? se_rb[q] : se_r[q];                                       \
      load_lds16(gb_ + (size_t)r_ * 4096 + ((TT) * 64 + (KH) * 32) * 2 + se_g[q] * 16, \
                 dst_ + dstoff[q]);                                              \
    }                                                                            \
  } while (0)

  #define QUAD(TT, KH, MSUB, READB) do {                                         \
    const char* ar_ = smem + ((TT) & 1) * 65536 + (KH) * 16384;                  \
    const char* br_ = ar_ + 32768;                                               \
    if (READB) {                                                                 \
      _Pragma("unroll")                                                          \
      for (int n = 0; n < 3; ++n)                                                \
        bfr[n] = *(const bf16x8*)(br_ + (wn * 24 + n * 8 + (lo >> 1)) * 128 + sw * 16); \
    }                                                                            \
    bf16x8 afr[4];                                                               \
    _Pragma("unroll")                                                            \
    for (int m = 0; m < 4; ++m)                                                  \
      afr[m] = *(const bf16x8*)(ar_ + (wm * 64 + (MSUB) * 32 + m * 8 + (lo >> 1)) * 128 + sw * 16); \
    __builtin_amdgcn_s_setprio(1);                                               \
    _Pragma("unroll")                                                            \
    for (int m = 0; m < 4; ++m)                                                  \
      _Pragma("unroll")                                                          \
      for (int n = 0; n < 3; ++n)                                                \
        acc[(MSUB) * 4 + m][n] =                                                 \
            __builtin_amdgcn_mfma_f32_16x16x32_bf16(afr[m], bfr[n], acc[(MSUB) * 4 + m][n], 0, 0, 0); \
    __builtin_amdgcn_s_setprio(0);                                               \
  } while (0)

  #define LGK0() asm volatile("s_waitcnt lgkmcnt(0)" ::: "memory")
  #define VMW8() asm volatile("s_waitcnt vmcnt(8)" ::: "memory")
  #define VMW4() asm volatile("s_waitcnt vmcnt(4)" ::: "memory")
  #define VMW0() asm volatile("s_waitcnt vmcnt(0)" ::: "memory")

  STG(0, 0, 0); STG(1, 0, 0);
  STG(0, 0, 1); STG(1, 0, 1);
  STG(0, 1, 0); STG(1, 1, 0);
  VMW8();
  wg_barrier();

  #define GITER(T0, LAST) do {                                                   \
    /* ph1 */ STG(0, (T0) + 1, 1); QUAD((T0), 0, 0, 1); wg_barrier();            \
    /* ph2 */ STG(1, (T0) + 1, 1); QUAD((T0), 0, 1, 0); LGK0(); VMW8(); wg_barrier(); \
    /* ph3 */ if (!(LAST)) { STG(0, (T0) + 2, 0); } QUAD((T0), 1, 0, 1); wg_barrier(); \
    /* ph4 */ if (!(LAST)) { STG(1, (T0) + 2, 0); } QUAD((T0), 1, 1, 0); LGK0(); \
              if (LAST) { VMW4(); } else { VMW8(); } wg_barrier();               \
    /* ph5 */ if (!(LAST)) { STG(0, (T0) + 2, 1); } QUAD((T0) + 1, 0, 0, 1); wg_barrier(); \
    /* ph6 */ if (!(LAST)) { STG(1, (T0) + 2, 1); } QUAD((T0) + 1, 0, 1, 0); LGK0(); \
              if (LAST) { VMW0(); } else { VMW8(); } wg_barrier();               \
    /* ph7 */ if (!(LAST)) { STG(0, (T0) + 3, 0); } QUAD((T0) + 1, 1, 0, 1); wg_barrier(); \
    /* ph8 */ if (!(LAST)) { STG(1, (T0) + 3, 0); } QUAD((T0) + 1, 1, 1, 0);     \
              if (!(LAST)) { LGK0(); VMW8(); wg_barrier(); }                     \
  } while (0)

  for (int i = 0; i < 15; ++i) GITER(2 * i, false);
  GITER(30, true);

  #undef GITER
  #undef STG
  #undef QUAD
  #undef VMW8
  #undef VMW4
  #undef LGK0
  #undef VMW0

  #pragma unroll
  for (int mm = 0; mm < 8; ++mm)
    #pragma unroll
    for (int n = 0; n < 3; ++n)
      #pragma unroll
      for (int r = 0; r < 4; ++r) {
        int row = bm + wm * 128 + mm * 16 + hi * 4 + r;
        int col = bn + wn * 48 + n * 16 + lo;
        C[(size_t)row * QKVW + col] = (__bf16)acc[mm][n][r];
      }
}

// ---- 8-phase final GEMM: out = Aq(Q cols, lda 6144) @ BTfused^T (R14-proven) ----
__global__ __launch_bounds__(512, 2)
void gemm_fin8(const __bf16* __restrict__ A, const __bf16* __restrict__ BT,
               float* __restrict__ C) {
  __shared__ __align__(16) char smem[98304];
  int tid = threadIdx.x;
  int w = tid >> 6, l = tid & 63, hi = l >> 4, lo = l & 15;
  int wm = w >> 2, wn = w & 3;
  int lin = blockIdx.x;
  int xcd = lin & 7, idx = lin >> 3;
  int cy = xcd >> 1, cx = xcd & 1;
  int iby = idx >> 2, ibx = idx & 3;
  int bm = (cy * 8 + iby) * 128;
  int bn = (cx * 4 + ibx) * 256;
  const char* Ab = (const char*)A + (size_t)bm * 12288;
  const char* Bb = (const char*)BT + (size_t)bn * 4096;

  int sw = (((lo & 1) << 2) + hi) ^ (lo >> 1);

  int se_r[2], se_g[2];
  #pragma unroll
  for (int q = 0; q < 2; ++q) {
    int e = q * 512 + tid;
    int lr = e >> 3, sl = e & 7;
    int x = sl ^ (lr & 7);
    se_r[q] = lr * 2 + (x >> 2);
    se_g[q] = x & 3;
  }
  int dstoff[2] = { (0 * 512 + w * 64) * 16, (1 * 512 + w * 64) * 16 };

  f32x4 acc[4][4];
  #pragma unroll
  for (int m = 0; m < 4; ++m)
    #pragma unroll
    for (int n = 0; n < 4; ++n) acc[m][n] = (f32x4){0.f, 0.f, 0.f, 0.f};
  bf16x8 bfr[4];

  #define STG(MAT, TT, KH) do {                                                  \
    char* ab_ = smem + ((TT) & 1) * 49152;                                       \
    char* dst_ = (MAT) ? (ab_ + 16384 + (KH) * 16384) : (ab_ + (KH) * 8192);     \
    const char* gb_ = (MAT) ? Bb : Ab;                                           \
    size_t ld_ = (MAT) ? 4096 : 12288;                                           \
    int nq_ = (MAT) ? 2 : 1;                                                     \
    _Pragma("unroll")                                                            \
    for (int q = 0; q < 2; ++q)                                                  \
      if (q < nq_)                                                               \
        load_lds16(gb_ + (size_t)se_r[q] * ld_ + ((TT) * 64 + (KH) * 32) * 2 + se_g[q] * 16, \
                   dst_ + dstoff[q]);                                            \
  } while (0)

  #define QUAD(TT, KH, MSUB, READB) do {                                         \
    const char* ab_ = smem + ((TT) & 1) * 49152;                                 \
    const char* ar_ = ab_ + (KH) * 8192;                                         \
    const char* br_ = ab_ + 16384 + (KH) * 16384;                                \
    if (READB) {                                                                 \
      _Pragma("unroll")                                                          \
      for (int n = 0; n < 4; ++n)                                                \
        bfr[n] = *(const bf16x8*)(br_ + (wn * 32 + n * 8 + (lo >> 1)) * 128 + sw * 16); \
    }                                                                            \
    bf16x8 afr[2];                                                               \
    _Pragma("unroll")                                                            \
    for (int m = 0; m < 2; ++m)                                                  \
      afr[m] = *(const bf16x8*)(ar_ + (wm * 32 + (MSUB) * 16 + m * 8 + (lo >> 1)) * 128 + sw * 16); \
    __builtin_amdgcn_s_setprio(1);                                               \
    _Pragma("unroll")                                                            \
    for (int m = 0; m < 2; ++m)                                                  \
      _Pragma("unroll")                                                          \
      for (int n = 0; n < 4; ++n)                                                \
        acc[(MSUB) * 2 + m][n] =                                                 \
            __builtin_amdgcn_mfma_f32_16x16x32_bf16(afr[m], bfr[n], acc[(MSUB) * 2 + m][n], 0, 0, 0); \
    __builtin_amdgcn_s_setprio(0);                                               \
  } while (0)

  #define LGK0() asm volatile("s_waitcnt lgkmcnt(0)" ::: "memory")
  #define VMW6() asm volatile("s_waitcnt vmcnt(6)" ::: "memory")
  #define VMW3() asm volatile("s_waitcnt vmcnt(3)" ::: "memory")
  #define VMW0() asm volatile("s_waitcnt vmcnt(0)" ::: "memory")

  STG(0, 0, 0); STG(1, 0, 0);
  STG(0, 0, 1); STG(1, 0, 1);
  STG(0, 1, 0); STG(1, 1, 0);
  VMW6();
  wg_barrier();

  #define GITER(T0, LAST) do {                                                   \
    /* ph1 */ STG(0, (T0) + 1, 1); QUAD((T0), 0, 0, 1); wg_barrier();            \
    /* ph2 */ STG(1, (T0) + 1, 1); QUAD((T0), 0, 1, 0); LGK0(); VMW6(); wg_barrier(); \
    /* ph3 */ if (!(LAST)) { STG(0, (T0) + 2, 0); } QUAD((T0), 1, 0, 1); wg_barrier(); \
    /* ph4 */ if (!(LAST)) { STG(1, (T0) + 2, 0); } QUAD((T0), 1, 1, 0); LGK0(); \
              if (LAST) { VMW3(); } else { VMW6(); } wg_barrier();               \
    /* ph5 */ if (!(LAST)) { STG(0, (T0) + 2, 1); } QUAD((T0) + 1, 0, 0, 1); wg_barrier(); \
    /* ph6 */ if (!(LAST)) { STG(1, (T0) + 2, 1); } QUAD((T0) + 1, 0, 1, 0); LGK0(); \
              if (LAST) { VMW0(); } else { VMW6(); } wg_barrier();               \
    /* ph7 */ if (!(LAST)) { STG(0, (T0) + 3, 0); } QUAD((T0) + 1, 1, 0, 1); wg_barrier(); \
    /* ph8 */ if (!(LAST)) { STG(1, (T0) + 3, 0); } QUAD((T0) + 1, 1, 1, 0);     \
              if (!(LAST)) { LGK0(); VMW6(); wg_barrier(); }                     \
  } while (0)

  for (int i = 0; i < 15; ++i) GITER(2 * i, false);
  GITER(30, true);

  #undef GITER
  #undef STG
  #undef QUAD
  #undef VMW6
  #undef VMW3
  #undef LGK0
  #undef VMW0

  #pragma unroll
  for (int mm = 0; mm < 4; ++mm)
    #pragma unroll
    for (int n = 0; n < 4; ++n)
      #pragma unroll
      for (int r = 0; r < 4; ++r) {
        int row = bm + wm * 64 + mm * 16 + hi * 4 + r;
        int col = bn + wn * 64 + n * 16 + lo;
        C[(size_t)row * 2048 + col] = acc[mm][n][r];
      }
}

// ---- phase-split counted-vmcnt GEMM (2-phase, for Mfused prep) ----
template<int BN, int NBY, int NBX, int CBY, int CBX, int KLEN, int LDA, int OUT_BF16>
__global__ __launch_bounds__(512, 2)
void gemm_ps(const __bf16* __restrict__ A, const __bf16* __restrict__ BT,
             void* __restrict__ Cout, int az, int cz, int ldc) {
  constexpr int FN = BN / 64;
  constexpr int LB = (BN > 128) ? 2 : 1;
  constexpr int VC = 2 + LB;
  constexpr int BUFSZ = 16384 + 8192 * LB;
  constexpr int CGX = NBX / CBX;
  static_assert((NBY / CBY) * CGX == 8, "chunk grid must be 8 XCDs");
  __shared__ __align__(16) char smem[2 * BUFSZ];
  int tid = threadIdx.x;
  int w = tid >> 6, l = tid & 63, hi = l >> 4, lo = l & 15;
  int wm = w >> 2, wn = w & 3;
  int lin = blockIdx.x;
  int xcd = lin & 7, idx = lin >> 3;
  int cy = xcd / CGX, cx = xcd % CGX;
  int iby = idx / CBX, ibx = idx % CBX;
  int bm = (cy * CBY + iby) * 256;
  int bn = (cx * CBX + ibx) * BN;
  const char* Ab = (const char*)(A + (size_t)blockIdx.y * az) + (size_t)bm * LDA * 2;
  const char* Bb = (const char*)BT + (size_t)bn * KLEN * 2;

  int sw = (((lo & 1) << 2) + hi) ^ (lo >> 1);
  int base_a = (wm * 64 + (lo >> 1)) * 128 + sw * 16;
  int base_b = 16384 + (wn * (BN / 8) + (lo >> 1)) * 128 + sw * 16;

  int se_r[2], se_g[2];
  #pragma unroll
  for (int q = 0; q < 2; ++q) {
    int e = q * 512 + tid;
    int lr = e >> 3, sl = e & 7;
    int x = sl ^ (lr & 7);
    se_r[q] = lr * 2 + (x >> 2);
    se_g[q] = x & 3;
  }
  int dstoff[2] = { (0 * 512 + w * 64) * 16, (1 * 512 + w * 64) * 16 };

  f32x4 acc[8][FN];
  #pragma unroll
  for (int m = 0; m < 8; ++m)
    #pragma unroll
    for (int n = 0; n < FN; ++n) acc[m][n] = (f32x4){0.f, 0.f, 0.f, 0.f};

  #define STAGE(BUFI, K0) do {                                                   \
    char* As_ = smem + (BUFI) * BUFSZ;                                           \
    char* Bs_ = As_ + 16384;                                                     \
    _Pragma("unroll")                                                            \
    for (int q = 0; q < 2; ++q)                                                  \
      load_lds16(Ab + (size_t)se_r[q] * (LDA * 2) + (size_t)(K0) * 2 + se_g[q] * 16, \
                 As_ + dstoff[q]);                                               \
    _Pragma("unroll")                                                            \
    for (int q = 0; q < LB; ++q)                                                 \
      load_lds16(Bb + (size_t)se_r[q] * (KLEN * 2) + (size_t)(K0) * 2 + se_g[q] * 16, \
                 Bs_ + dstoff[q]);                                               \
  } while (0)

  #define WAITVC() do {                                                \
    if constexpr (VC == 4) asm volatile("s_waitcnt vmcnt(4)" ::: "memory"); \
    else                   asm volatile("s_waitcnt vmcnt(3)" ::: "memory"); \
  } while (0)

  constexpr int NT = KLEN / 32;
  STAGE(0, 0);
  STAGE(1, 32);
  WAITVC();
  wg_barrier();

  for (int t = 0; t < NT; ++t) {
    char* buf = smem + (t & 1) * BUFSZ;
    bf16x8 bfr[FN], afr[8];
    #pragma unroll
    for (int n = 0; n < FN; ++n) bfr[n] = *(const bf16x8*)(buf + base_b + n * 1024);
    #pragma unroll
    for (int m = 0; m < 8; ++m) afr[m] = *(const bf16x8*)(buf + base_a + m * 1024);
    __builtin_amdgcn_s_setprio(1);
    #pragma unroll
    for (int m = 0; m < 4; ++m)
      #pragma unroll
      for (int n = 0; n < FN; ++n)
        acc[m][n] = __builtin_amdgcn_mfma_f32_16x16x32_bf16(afr[m], bfr[n], acc[m][n], 0, 0, 0);
    __builtin_amdgcn_s_setprio(0);
    asm volatile("s_waitcnt lgkmcnt(0)" ::: "memory");
    wg_barrier();

    if (t + 2 < NT) STAGE(t & 1, (t + 2) * 32);
    __builtin_amdgcn_s_setprio(1);
    #pragma unroll
    for (int m = 4; m < 8; ++m)
      #pragma unroll
      for (int n = 0; n < FN; ++n)
        acc[m][n] = __builtin_amdgcn_mfma_f32_16x16x32_bf16(afr[m], bfr[n], acc[m][n], 0, 0, 0);
    __builtin_amdgcn_s_setprio(0);
    if (t + 2 < NT) { WAITVC(); }
    else            { asm volatile("s_waitcnt vmcnt(0)" ::: "memory"); }
    wg_barrier();
  }
  #undef STAGE
  #undef WAITVC

  #pragma unroll
  for (int m = 0; m < 8; ++m)
    #pragma unroll
    for (int n = 0; n < FN; ++n)
      #pragma unroll
      for (int r = 0; r < 4; ++r) {
        int row = bm + wm * 128 + m * 16 + hi * 4 + r;
        int col = bn + wn * (BN / 4) + n * 16 + lo;
        if (OUT_BF16)
          ((__bf16*)Cout)[(size_t)blockIdx.y * cz + (size_t)row * ldc + col] = (__bf16)acc[m][n][r];
        else
          ((float*)Cout)[(size_t)blockIdx.y * cz + (size_t)row * ldc + col] = acc[m][n][r];
      }
}

// ---- fused: RoPE on Q,K cols (blocks 0..4095) + V transpose (4096..5119) ----
__global__ __launch_bounds__(256)
void rope_transv(__bf16* __restrict__ QKV, const float* __restrict__ fc,
                 const float* __restrict__ fs, __bf16* __restrict__ VT) {
  __shared__ __bf16 tile[64][136];
  int tid = threadIdx.x;
  if (blockIdx.x < 4096) {
    int idx = blockIdx.x * 256 + tid;
    int pg = idx & 15;
    int h = (idx >> 4) & 15;
    int n = idx >> 8;
    int t = n & 1023;
    float4 c4 = *(const float4*)(fc + t * 64 + pg * 4);
    float4 s4 = *(const float4*)(fs + t * 64 + pg * 4);
    float c[4] = {c4.x, c4.y, c4.z, c4.w};
    float s[4] = {s4.x, s4.y, s4.z, s4.w};
    size_t ofs = (size_t)n * QKVW + h * 128 + pg * 8;
    bf16x8 q = *(bf16x8*)(QKV + ofs);
    bf16x8 k = *(bf16x8*)(QKV + 2048 + ofs);
    bf16x8 oq, ok;
    #pragma unroll
    for (int j = 0; j < 4; ++j) {
      float x = (float)q[2 * j], y = (float)q[2 * j + 1];
      oq[2 * j]     = (__bf16)(x * c[j] - y * s[j]);
      oq[2 * j + 1] = (__bf16)(x * s[j] + y * c[j]);
      float u = (float)k[2 * j], vv = (float)k[2 * j + 1];
      ok[2 * j]     = (__bf16)(u * c[j] - vv * s[j]);
      ok[2 * j + 1] = (__bf16)(u * s[j] + vv * c[j]);
    }
    *(bf16x8*)(QKV + ofs) = oq;
    *(bf16x8*)(QKV + 2048 + ofs) = ok;
    return;
  }
  int bid = blockIdx.x - 4096;
  int tt = bid & 15;
  int bh = bid >> 4;
  int b = bh >> 4, h = bh & 15;
  int t0 = tt * 64;
  #pragma unroll
  for (int q = 0; q < 4; ++q) {
    int i = q * 256 + tid;
    int tr = i >> 4, u = i & 15;
    bf16x8 v = *(const bf16x8*)(QKV + (size_t)(b * 1024 + t0 + tr) * QKVW + 4096 + h * 128 + u * 8);
    *(bf16x8*)&tile[tr][u * 8] = v;
  }
  __syncthreads();
  #pragma unroll
  for (int q = 0; q < 4; ++q) {
    int i = q * 256 + tid;
    int d = i >> 3, tu = i & 7;
    bf16x8 o;
    #pragma unroll
    for (int jj = 0; jj < 8; ++jj) o[jj] = tile[tu * 8 + jj][d];
    *(bf16x8*)(VT + ((size_t)bh * 128 + d) * 1024 + t0 + tu * 8) = o;
  }
}

// ---- 32x32 MFMA flash attention, causal, dbuf async staging ----
__global__ __launch_bounds__(256, 2)
void attn_mfma2(__bf16* __restrict__ QKV, const __bf16* __restrict__ VT) {
  __shared__ __align__(16) char smem[65536];
  int tid = threadIdx.x;
  int w = tid >> 6, l = tid & 63;
  int lo = l & 31, hv = l >> 5;
  int wgid = blockIdx.x;
  int xcd = wgid & 7, idx = wgid >> 3;
  int s = idx & 7, j = s >> 1, odd = s & 1, hi5 = idx >> 5;
  int base = hi5 ? 7 - j : j;
  int qt = odd ? 7 - base : base;
  int bh = xcd * 8 + (idx >> 3);
  int b = bh >> 4, h = bh & 15;
  int qb = qt * 128;
  int wq0 = qb + w * 32;
  int qrow = wq0 + lo;
  const __bf16* qp = QKV + (size_t)(b * 1024 + qrow) * QKVW + h * 128;
  bf16x8 qf[8];
  #pragma unroll
  for (int c = 0; c < 8; ++c) qf[c] = *(const bf16x8*)(qp + c * 16 + hv * 8);

  f32x16 o[4];
  #pragma unroll
  for (int n = 0; n < 4; ++n)
    #pragma unroll
    for (int r = 0; r < 16; ++r) o[n][r] = 0.f;
  float mrun = -1e30f, lrun = 0.f;
  const float SCL = 0.08838834764831845f * 1.4426950408889634f;
  int src0 = lo, src1 = 32 + lo;
  int nt = 2 * qt + 2;

  #define ASTAGE(BUF, KT) do {                                                   \
    _Pragma("unroll")                                                            \
    for (int i = 0; i < 4; ++i) {                                                \
      int e = i * 256 + tid;                                                     \
      int row = e >> 4, g = e & 15;                                              \
      int gs = g ^ (row & 7);                                                    \
      const char* src = (const char*)QKV +                                       \
          ((size_t)(b * 1024 + (KT) * 64 + row) * QKVW + 2048 + h * 128) * 2 + gs * 16; \
      load_lds16(src, smem + (BUF) * 16384 + (i * 256 + w * 64) * 16);           \
    }                                                                            \
    _Pragma("unroll")                                                            \
    for (int i = 0; i < 4; ++i) {                                                \
      int e = i * 256 + tid;                                                     \
      int row = e >> 3, g = e & 7;                                               \
      int gs = g ^ (row & 7);                                                    \
      const char* src = (const char*)VT +                                        \
          ((size_t)(bh * 128 + row) * 1024 + (KT) * 64) * 2 + gs * 16;           \
      load_lds16(src, smem + 32768 + (BUF) * 16384 + (i * 256 + w * 64) * 16);   \
    }                                                                            \
  } while (0)

  ASTAGE(0, 0);
  asm volatile("s_waitcnt vmcnt(0)" ::: "memory");
  wg_barrier();

  for (int kt = 0; kt < nt; ++kt) {
    int cur = kt & 1;
    if (kt + 1 < nt) ASTAGE(cur ^ 1, kt + 1);
    int k0 = kt * 64;
    char* Ks  = smem + cur * 16384;
    char* VTs = smem + 32768 + cur * 16384;

    if (k0 <= wq0 + 31) {
      f32x16 sT[2];
      #pragma unroll
      for (int kk = 0; kk < 2; ++kk) {
        #pragma unroll
        for (int r = 0; r < 16; ++r) sT[kk][r] = 0.f;
        #pragma unroll
        for (int c = 0; c < 8; ++c) {
          bf16x8 kf = *(const bf16x8*)(Ks + (kk * 32 + lo) * 256 + (((2 * c + hv) ^ (lo & 7)) * 16));
          sT[kk] = __builtin_amdgcn_mfma_f32_32x32x16_bf16(kf, qf[c], sT[kk], 0, 0, 0);
        }
      }
      bool diag = (k0 + 63 > wq0);
      float pv[2][16];
      #pragma unroll
      for (int kk = 0; kk < 2; ++kk)
        #pragma unroll
        for (int r = 0; r < 16; ++r) {
          float v = sT[kk][r] * SCL;
          if (diag) {
            int kg = k0 + kk * 32 + (r & 3) + 8 * (r >> 2) + 4 * hv;
            if (kg > qrow) v = -1e30f;
          }
          pv[kk][r] = v;
        }
      float mx = pv[0][0];
      #pragma unroll
      for (int kk = 0; kk < 2; ++kk)
        #pragma unroll
        for (int r = 0; r < 16; ++r) mx = fmaxf(mx, pv[kk][r]);
      mx = fmaxf(mx, __shfl_xor(mx, 32, 64));
      if (!__all(mx <= mrun + 8.f)) {
        float mnew = fmaxf(mrun, mx);
        float fac = exp2f(mrun - mnew);
        lrun *= fac;
        #pragma unroll
        for (int n = 0; n < 4; ++n)
          #pragma unroll
          for (int r = 0; r < 16; ++r) o[n][r] *= fac;
        mrun = mnew;
      }
      float rs = 0.f;
      #pragma unroll
      for (int kk = 0; kk < 2; ++kk)
        #pragma unroll
        for (int r = 0; r < 16; ++r) {
          float p = exp2f(pv[kk][r] - mrun);
          pv[kk][r] = p;
          rs += p;
        }
      rs += __shfl_xor(rs, 32, 64);
      lrun += rs;

      unsigned pk[2][4][2];
      #pragma unroll
      for (int kk = 0; kk < 2; ++kk)
        #pragma unroll
        for (int m = 0; m < 4; ++m)
          #pragma unroll
          for (int u = 0; u < 2; ++u)
            pk[kk][m][u] = pack2(pv[kk][m * 4 + 2 * u], pv[kk][m * 4 + 2 * u + 1]);

      #pragma unroll
      for (int kk = 0; kk < 2; ++kk) {
        #pragma unroll
        for (int s2 = 0; s2 < 2; ++s2) {
          unsigned a0 = __shfl(pk[kk][2 * s2][0], src0, 64);
          unsigned b0 = __shfl(pk[kk][2 * s2 + 1][0], src0, 64);
          unsigned a1 = __shfl(pk[kk][2 * s2][1], src0, 64);
          unsigned b1 = __shfl(pk[kk][2 * s2 + 1][1], src0, 64);
          unsigned a2 = __shfl(pk[kk][2 * s2][0], src1, 64);
          unsigned b2 = __shfl(pk[kk][2 * s2 + 1][0], src1, 64);
          unsigned a3 = __shfl(pk[kk][2 * s2][1], src1, 64);
          unsigned b3 = __shfl(pk[kk][2 * s2 + 1][1], src1, 64);
          union { unsigned u[4]; bf16x8 v; } pb;
          pb.u[0] = hv ? b0 : a0;
          pb.u[1] = hv ? b1 : a1;
          pb.u[2] = hv ? b2 : a2;
          pb.u[3] = hv ? b3 : a3;
          int ks16 = 2 * kk + s2;
          #pragma unroll
          for (int n = 0; n < 4; ++n) {
            bf16x8 vf = *(const bf16x8*)(VTs + (n * 32 + lo) * 128 +
                                         (((2 * ks16 + hv) ^ (lo & 7)) * 16));
            o[n] = __builtin_amdgcn_mfma_f32_32x32x16_bf16(vf, pb.v, o[n], 0, 0, 0);
          }
        }
      }
    }
    asm volatile("s_waitcnt vmcnt(0)" ::: "memory");
    wg_barrier();
  }
  #undef ASTAGE

  float inv = 1.f / lrun;
  __bf16* op = QKV + (size_t)(b * 1024 + qrow) * QKVW + h * 128;
  #pragma unroll
  for (int n = 0; n < 4; ++n)
    #pragma unroll
    for (int m4 = 0; m4 < 4; ++m4) {
      bf16x4 ov;
      #pragma unroll
      for (int jj = 0; jj < 4; ++jj) ov[jj] = (__bf16)(o[n][m4 * 4 + jj] * inv);
      *(bf16x4*)(op + n * 32 + 8 * m4 + 4 * hv) = ov;
    }
}

extern "C" void kernel_launch(void* const* d_in, const int* in_sizes, int n_in,
                              void* d_out, int out_size, void* d_ws, size_t ws_size,
                              hipStream_t stream) {
  const float* x    = (const float*)d_in[0];
  const float* fc   = (const float*)d_in[1];
  const float* fs   = (const float*)d_in[2];
  const float* wq   = (const float*)d_in[3];
  const float* wk   = (const float*)d_in[4];
  const float* wv   = (const float*)d_in[5];
  const float* wo   = (const float*)d_in[6];
  const float* wm   = (const float*)d_in[7];
  const float* beta = (const float*)d_in[8];

  char* wsb = (char*)d_ws;
  __bf16* xb      = (__bf16*)(wsb);
  __bf16* MTqkv   = (__bf16*)(wsb + 16777216L);
  __bf16* QKV     = (__bf16*)(wsb + 41943040L);
  __bf16* VTb     = (__bf16*)(wsb + 92274688L);
  double* s8      = (double*)(wsb + 109051904L);
  double* part    = (double*)(wsb + 109052160L);
  double* rs8     = (double*)(wsb + 109054208L);
  __bf16* MTwo    = (__bf16*)(wsb);
  __bf16* BTfused = (__bf16*)(wsb + 8388608L);
  __bf16* MTmixP  = MTqkv;

  dim3 blk(256);

  cast_scale<<<8448, blk, 0, stream>>>(x, xb, wq, wk, wv, wo, part);
  scale_fin<<<1, dim3(64), 0, stream>>>(part, s8, rs8);
  build_oct3<<<dim3(16384, 3), blk, 0, stream>>>(wq, wk, wv, s8, rs8, MTqkv);

  // QKV = xb @ [Mq|Mk|Mv]^T (R14-proven, no RoPE fusion)
  gemm_qkv8<<<512, dim3(512), 0, stream>>>(xb, MTqkv, QKV);

  // fold mixer into final weight (MoT + mixer built in one dispatch)
  build_wo_mix<<<20480, blk, 0, stream>>>(wo, s8 + 24, rs8 + 24, MTwo, wm, beta, MTmixP);
  gemm_ps<128, 8, 8, 2, 4, 1024, 2048, 1>
      <<<dim3(64, 2), dim3(512), 0, stream>>>(MTwo, MTmixP, BTfused, 1024, 1024, 2048);

  // RoPE (Q,K) + V transpose in one dispatch
  rope_transv<<<5120, blk, 0, stream>>>(QKV, fc, fs, VTb);

  attn_mfma2<<<dim3(512), blk, 0, stream>>>(QKV, VTb);

  // out = attn_out @ Mfused (8-phase final GEMM)
  gemm_fin8<<<256, dim3(512), 0, stream>>>(QKV, BTfused, (float*)d_out);
}

// Round 17
// 295.955 us; speedup vs baseline: 1.0848x; 1.0257x over previous
//
#include <hip/hip_runtime.h>
#include <math.h>

#define CDIM 2048
#define QKVW 6144

typedef __bf16 bf16x8 __attribute__((ext_vector_type(8)));
typedef __bf16 bf16x4 __attribute__((ext_vector_type(4)));
typedef float  f32x4  __attribute__((ext_vector_type(4)));
typedef float  f32x16 __attribute__((ext_vector_type(16)));

__device__ __constant__ float SIGNS_c[64] = {
  1,  1,  1,  1,  1,  1,  1,  1,
  1, -1,  1, -1,  1, -1, -1,  1,
  1, -1, -1,  1,  1,  1, -1, -1,
  1,  1, -1, -1,  1, -1,  1, -1,
  1, -1, -1, -1, -1,  1,  1,  1,
  1,  1, -1,  1, -1, -1, -1,  1,
  1,  1,  1, -1, -1,  1, -1, -1,
  1, -1,  1,  1, -1, -1,  1, -1
};

__device__ __forceinline__ void load_lds16(const void* g, void* lp) {
  __builtin_amdgcn_global_load_lds(
      (const __attribute__((address_space(1))) unsigned int*)g,
      (__attribute__((address_space(3))) unsigned int*)lp, 16, 0, 0);
}

__device__ __forceinline__ void wg_barrier() {
  asm volatile("" ::: "memory");
  __builtin_amdgcn_s_barrier();
  asm volatile("" ::: "memory");
}

__device__ __forceinline__ unsigned pack2(float a, float b) {
  union { __bf16 h[2]; unsigned u; } x;
  x.h[0] = (__bf16)a; x.h[1] = (__bf16)b; return x.u;
}

// ---- fused: cast x -> bf16 (blocks 0..8191) + partial |W| sums (8192..8447) ----
__global__ __launch_bounds__(256)
void cast_scale(const float* __restrict__ x, __bf16* __restrict__ xb,
                const float* __restrict__ wq, const float* __restrict__ wk,
                const float* __restrict__ wv, const float* __restrict__ wo,
                double* __restrict__ part) {
  __shared__ double red[256];
  if (blockIdx.x < 8192) {
    int i = blockIdx.x * 256 + threadIdx.x;
    float4 v = *(const float4*)(x + (size_t)i * 4);
    bf16x4 o;
    o[0] = (__bf16)v.x; o[1] = (__bf16)v.y; o[2] = (__bf16)v.z; o[3] = (__bf16)v.w;
    *(bf16x4*)(xb + (size_t)i * 4) = o;
    return;
  }
  int bid = blockIdx.x - 8192;
  int which = bid >> 6, m = (bid >> 3) & 7, seg = bid & 7;
  const float* W = (which == 0) ? wq : (which == 1) ? wk : (which == 2) ? wv : wo;
  const float4* w4 = (const float4*)(W + (m << 16) + seg * 8192);
  double acc = 0.0;
  #pragma unroll
  for (int i = 0; i < 8; ++i) {
    float4 v = w4[threadIdx.x + i * 256];
    acc += (double)fabsf(v.x) + (double)fabsf(v.y) +
           (double)fabsf(v.z) + (double)fabsf(v.w);
  }
  red[threadIdx.x] = acc;
  __syncthreads();
  for (int s = 128; s > 0; s >>= 1) {
    if (threadIdx.x < s) red[threadIdx.x] += red[threadIdx.x + s];
    __syncthreads();
  }
  if (threadIdx.x == 0) part[bid] = red[0];
}

// ---- fixed-order final sum + reciprocal (deterministic) ----
__global__ void scale_fin(const double* __restrict__ part, double* __restrict__ s8,
                          double* __restrict__ rs8) {
  int t = threadIdx.x;
  if (t < 32) {
    double a = 0.0;
    #pragma unroll
    for (int i = 0; i < 8; ++i) a += part[t * 8 + i];
    double s = a / 65536.0 + 1e-8;
    s8[t] = s;
    rs8[t] = 1.0 / s;
  }
}

__global__ void build_oct3(const float* __restrict__ wq, const float* __restrict__ wk,
                           const float* __restrict__ wv, const double* __restrict__ s8,
                           const double* __restrict__ rs8, __bf16* __restrict__ MT) {
  int z = blockIdx.y;
  const float* W = (z == 0) ? wq : (z == 1) ? wk : wv;
  const double* sp = s8 + z * 8;
  const double* rp = rs8 + z * 8;
  __bf16* out = MT + (size_t)z * 4194304;
  int idx = blockIdx.x * 256 + threadIdx.x;
  int row = idx & 2047, col = idx >> 11;
  int i = col >> 8, d = col & 255, j = row >> 8, c = row & 255;
  int m = i ^ j;
  double q = rint((double)W[(m << 16) + (c << 8) + d] * rp[m]);
  q = fmin(fmax(q, -1.0), 1.0);
  out[idx] = (__bf16)(SIGNS_c[i * 8 + j] * (float)(q * sp[m]));
}

// ---- fused: MoT build (blocks 0..16383) + mixer plain build (16384..20479) ----
__global__ void build_wo_mix(const float* __restrict__ W, const double* __restrict__ s8,
                             const double* __restrict__ rs8, __bf16* __restrict__ MT,
                             const float* __restrict__ Wm, const float* __restrict__ beta,
                             __bf16* __restrict__ Mmix) {
  if (blockIdx.x < 16384) {
    int idx = blockIdx.x * 256 + threadIdx.x;
    int row = idx & 2047, col = idx >> 11;
    int i = col >> 8, d = col & 255, j = row >> 8, c = row & 255;
    int m = i ^ j;
    double q = rint((double)W[(m << 16) + (c << 8) + d] * rs8[m]);
    q = fmin(fmax(q, -1.0), 1.0);
    MT[idx] = (__bf16)(SIGNS_c[i * 8 + j] * (float)(q * s8[m]));
    return;
  }
  int idx = (blockIdx.x - 16384) * 256 + threadIdx.x;
  int kl = idx & 1023, kpl = idx >> 10;
  int j = kpl >> 7, dd = kpl & 127;
  int i = kl >> 7, e = kl & 127;
  Mmix[idx] = (__bf16)(SIGNS_c[i * 8 + j] * Wm[((i ^ j) << 14) + (dd << 7) + e] * beta[e]);
}

// ---- 8-phase 256x192 BK=64 GEMM for QKV; V cols written transposed to VT ----
__global__ __launch_bounds__(512, 2)
void gemm_qkv8(const __bf16* __restrict__ A, const __bf16* __restrict__ BT,
               __bf16* __restrict__ C, __bf16* __restrict__ VT) {
  __shared__ __align__(16) char smem[131072];
  int tid = threadIdx.x;
  int w = tid >> 6, l = tid & 63, hi = l >> 4, lo = l & 15;
  int wm = w >> 2, wn = w & 3;
  int lin = blockIdx.x;
  int xcd = lin & 7, idx = lin >> 3;
  int cy = xcd >> 2, cx = xcd & 3;
  int iby = idx >> 3, ibx = idx & 7;
  int bm = (cy * 8 + iby) * 256;
  int bn = (cx * 8 + ibx) * 192;
  const char* Ab = (const char*)A + (size_t)bm * 4096;
  const char* Bb = (const char*)BT + (size_t)bn * 4096;

  int sw = (((lo & 1) << 2) + hi) ^ (lo >> 1);

  int se_r[2], se_g[2], se_rb[2];
  #pragma unroll
  for (int q = 0; q < 2; ++q) {
    int e = q * 512 + tid;
    int lr = e >> 3, sl = e & 7;
    int x = sl ^ (lr & 7);
    se_r[q] = lr * 2 + (x >> 2);
    se_g[q] = x & 3;
    se_rb[q] = se_r[q] < 192 ? se_r[q] : 191;
  }
  int dstoff[2] = { (0 * 512 + w * 64) * 16, (1 * 512 + w * 64) * 16 };

  f32x4 acc[8][3];
  #pragma unroll
  for (int m = 0; m < 8; ++m)
    #pragma unroll
    for (int n = 0; n < 3; ++n) acc[m][n] = (f32x4){0.f, 0.f, 0.f, 0.f};
  bf16x8 bfr[3];

  #define STG(MAT, TT, KH) do {                                                  \
    char* dst_ = smem + ((TT) & 1) * 65536 + (MAT) * 32768 + (KH) * 16384;       \
    const char* gb_ = (MAT) ? Bb : Ab;                                           \
    _Pragma("unroll")                                                            \
    for (int q = 0; q < 2; ++q) {                                                \
      int r_ = (MAT) ? se_rb[q] : se_r[q];                                       \
      load_lds16(gb_ + (size_t)r_ * 4096 + ((TT) * 64 + (KH) * 32) * 2 + se_g[q] * 16, \
                 dst_ + dstoff[q]);                                              \
    }                                                                            \
  } while (0)

  #define QUAD(TT, KH, MSUB, READB) do {                                         \
    const char* ar_ = smem + ((TT) & 1) * 65536 + (KH) * 16384;                  \
    const char* br_ = ar_ + 32768;                                               \
    if (READB) {                                                                 \
      _Pragma("unroll")                                                          \
      for (int n = 0; n < 3; ++n)                                                \
        bfr[n] = *(const bf16x8*)(br_ + (wn * 24 + n * 8 + (lo >> 1)) * 128 + sw * 16); \
    }                                                                            \
    bf16x8 afr[4];                                                               \
    _Pragma("unroll")                                                            \
    for (int m = 0; m < 4; ++m)                                                  \
      afr[m] = *(const bf16x8*)(ar_ + (wm * 64 + (MSUB) * 32 + m * 8 + (lo >> 1)) * 128 + sw * 16); \
    __builtin_amdgcn_s_setprio(1);                                               \
    _Pragma("unroll")                                                            \
    for (int m = 0; m < 4; ++m)                                                  \
      _Pragma("unroll")                                                          \
      for (int n = 0; n < 3; ++n)                                                \
        acc[(MSUB) * 4 + m][n] =                                                 \
            __builtin_amdgcn_mfma_f32_16x16x32_bf16(afr[m], bfr[n], acc[(MSUB) * 4 + m][n], 0, 0, 0); \
    __builtin_amdgcn_s_setprio(0);                                               \
  } while (0)

  #define LGK0() asm volatile("s_waitcnt lgkmcnt(0)" ::: "memory")
  #define VMW8() asm volatile("s_waitcnt vmcnt(8)" ::: "memory")
  #define VMW4() asm volatile("s_waitcnt vmcnt(4)" ::: "memory")
  #define VMW0() asm volatile("s_waitcnt vmcnt(0)" ::: "memory")

  STG(0, 0, 0); STG(1, 0, 0);
  STG(0, 0, 1); STG(1, 0, 1);
  STG(0, 1, 0); STG(1, 1, 0);
  VMW8();
  wg_barrier();

  #define GITER(T0, LAST) do {                                                   \
    /* ph1 */ STG(0, (T0) + 1, 1); QUAD((T0), 0, 0, 1); wg_barrier();            \
    /* ph2 */ STG(1, (T0) + 1, 1); QUAD((T0), 0, 1, 0); LGK0(); VMW8(); wg_barrier(); \
    /* ph3 */ if (!(LAST)) { STG(0, (T0) + 2, 0); } QUAD((T0), 1, 0, 1); wg_barrier(); \
    /* ph4 */ if (!(LAST)) { STG(1, (T0) + 2, 0); } QUAD((T0), 1, 1, 0); LGK0(); \
              if (LAST) { VMW4(); } else { VMW8(); } wg_barrier();               \
    /* ph5 */ if (!(LAST)) { STG(0, (T0) + 2, 1); } QUAD((T0) + 1, 0, 0, 1); wg_barrier(); \
    /* ph6 */ if (!(LAST)) { STG(1, (T0) + 2, 1); } QUAD((T0) + 1, 0, 1, 0); LGK0(); \
              if (LAST) { VMW0(); } else { VMW8(); } wg_barrier();               \
    /* ph7 */ if (!(LAST)) { STG(0, (T0) + 3, 0); } QUAD((T0) + 1, 1, 0, 1); wg_barrier(); \
    /* ph8 */ if (!(LAST)) { STG(1, (T0) + 3, 0); } QUAD((T0) + 1, 1, 1, 0);     \
              if (!(LAST)) { LGK0(); VMW8(); wg_barrier(); }                     \
  } while (0)

  for (int i = 0; i < 15; ++i) GITER(2 * i, false);
  GITER(30, true);

  #undef GITER
  #undef STG
  #undef QUAD
  #undef VMW8
  #undef VMW4
  #undef LGK0
  #undef VMW0

  // epilogue: Q/K cols -> QKV rows; V cols -> VT transposed (r -> consecutive t)
  #pragma unroll
  for (int mm = 0; mm < 8; ++mm)
    #pragma unroll
    for (int n = 0; n < 3; ++n) {
      int col = bn + wn * 48 + n * 16 + lo;
      int row0 = bm + wm * 128 + mm * 16 + hi * 4;
      if (col < 4096) {
        #pragma unroll
        for (int r = 0; r < 4; ++r)
          C[(size_t)(row0 + r) * QKVW + col] = (__bf16)acc[mm][n][r];
      } else {
        int v = col - 4096;
        int bh = (row0 >> 10) * 16 + (v >> 7);
        int dd = v & 127;
        int t0 = row0 & 1023;
        bf16x4 ov;
        #pragma unroll
        for (int r = 0; r < 4; ++r) ov[r] = (__bf16)acc[mm][n][r];
        *(bf16x4*)(VT + ((size_t)bh * 128 + dd) * 1024 + t0) = ov;
      }
    }
}

// ---- 8-phase final GEMM: out = Aq(Q cols, lda 6144) @ BTfused^T (R14-proven) ----
__global__ __launch_bounds__(512, 2)
void gemm_fin8(const __bf16* __restrict__ A, const __bf16* __restrict__ BT,
               float* __restrict__ C) {
  __shared__ __align__(16) char smem[98304];
  int tid = threadIdx.x;
  int w = tid >> 6, l = tid & 63, hi = l >> 4, lo = l & 15;
  int wm = w >> 2, wn = w & 3;
  int lin = blockIdx.x;
  int xcd = lin & 7, idx = lin >> 3;
  int cy = xcd >> 1, cx = xcd & 1;
  int iby = idx >> 2, ibx = idx & 3;
  int bm = (cy * 8 + iby) * 128;
  int bn = (cx * 4 + ibx) * 256;
  const char* Ab = (const char*)A + (size_t)bm * 12288;
  const char* Bb = (const char*)BT + (size_t)bn * 4096;

  int sw = (((lo & 1) << 2) + hi) ^ (lo >> 1);

  int se_r[2], se_g[2];
  #pragma unroll
  for (int q = 0; q < 2; ++q) {
    int e = q * 512 + tid;
    int lr = e >> 3, sl = e & 7;
    int x = sl ^ (lr & 7);
    se_r[q] = lr * 2 + (x >> 2);
    se_g[q] = x & 3;
  }
  int dstoff[2] = { (0 * 512 + w * 64) * 16, (1 * 512 + w * 64) * 16 };

  f32x4 acc[4][4];
  #pragma unroll
  for (int m = 0; m < 4; ++m)
    #pragma unroll
    for (int n = 0; n < 4; ++n) acc[m][n] = (f32x4){0.f, 0.f, 0.f, 0.f};
  bf16x8 bfr[4];

  #define STG(MAT, TT, KH) do {                                                  \
    char* ab_ = smem + ((TT) & 1) * 49152;                                       \
    char* dst_ = (MAT) ? (ab_ + 16384 + (KH) * 16384) : (ab_ + (KH) * 8192);     \
    const char* gb_ = (MAT) ? Bb : Ab;                                           \
    size_t ld_ = (MAT) ? 4096 : 12288;                                           \
    int nq_ = (MAT) ? 2 : 1;                                                     \
    _Pragma("unroll")                                                            \
    for (int q = 0; q < 2; ++q)                                                  \
      if (q < nq_)                                                               \
        load_lds16(gb_ + (size_t)se_r[q] * ld_ + ((TT) * 64 + (KH) * 32) * 2 + se_g[q] * 16, \
                   dst_ + dstoff[q]);                                            \
  } while (0)

  #define QUAD(TT, KH, MSUB, READB) do {                                         \
    const char* ab_ = smem + ((TT) & 1) * 49152;                                 \
    const char* ar_ = ab_ + (KH) * 8192;                                         \
    const char* br_ = ab_ + 16384 + (KH) * 16384;                                \
    if (READB) {                                                                 \
      _Pragma("unroll")                                                          \
      for (int n = 0; n < 4; ++n)                                                \
        bfr[n] = *(const bf16x8*)(br_ + (wn * 32 + n * 8 + (lo >> 1)) * 128 + sw * 16); \
    }                                                                            \
    bf16x8 afr[2];                                                               \
    _Pragma("unroll")                                                            \
    for (int m = 0; m < 2; ++m)                                                  \
      afr[m] = *(const bf16x8*)(ar_ + (wm * 32 + (MSUB) * 16 + m * 8 + (lo >> 1)) * 128 + sw * 16); \
    __builtin_amdgcn_s_setprio(1);                                               \
    _Pragma("unroll")                                                            \
    for (int m = 0; m < 2; ++m)                                                  \
      _Pragma("unroll")                                                          \
      for (int n = 0; n < 4; ++n)                                                \
        acc[(MSUB) * 2 + m][n] =                                                 \
            __builtin_amdgcn_mfma_f32_16x16x32_bf16(afr[m], bfr[n], acc[(MSUB) * 2 + m][n], 0, 0, 0); \
    __builtin_amdgcn_s_setprio(0);                                               \
  } while (0)

  #define LGK0() asm volatile("s_waitcnt lgkmcnt(0)" ::: "memory")
  #define VMW6() asm volatile("s_waitcnt vmcnt(6)" ::: "memory")
  #define VMW3() asm volatile("s_waitcnt vmcnt(3)" ::: "memory")
  #define VMW0() asm volatile("s_waitcnt vmcnt(0)" ::: "memory")

  STG(0, 0, 0); STG(1, 0, 0);
  STG(0, 0, 1); STG(1, 0, 1);
  STG(0, 1, 0); STG(1, 1, 0);
  VMW6();
  wg_barrier();

  #define GITER(T0, LAST) do {                                                   \
    /* ph1 */ STG(0, (T0) + 1, 1); QUAD((T0), 0, 0, 1); wg_barrier();            \
    /* ph2 */ STG(1, (T0) + 1, 1); QUAD((T0), 0, 1, 0); LGK0(); VMW6(); wg_barrier(); \
    /* ph3 */ if (!(LAST)) { STG(0, (T0) + 2, 0); } QUAD((T0), 1, 0, 1); wg_barrier(); \
    /* ph4 */ if (!(LAST)) { STG(1, (T0) + 2, 0); } QUAD((T0), 1, 1, 0); LGK0(); \
              if (LAST) { VMW3(); } else { VMW6(); } wg_barrier();               \
    /* ph5 */ if (!(LAST)) { STG(0, (T0) + 2, 1); } QUAD((T0) + 1, 0, 0, 1); wg_barrier(); \
    /* ph6 */ if (!(LAST)) { STG(1, (T0) + 2, 1); } QUAD((T0) + 1, 0, 1, 0); LGK0(); \
              if (LAST) { VMW0(); } else { VMW6(); } wg_barrier();               \
    /* ph7 */ if (!(LAST)) { STG(0, (T0) + 3, 0); } QUAD((T0) + 1, 1, 0, 1); wg_barrier(); \
    /* ph8 */ if (!(LAST)) { STG(1, (T0) + 3, 0); } QUAD((T0) + 1, 1, 1, 0);     \
              if (!(LAST)) { LGK0(); VMW6(); wg_barrier(); }                     \
  } while (0)

  for (int i = 0; i < 15; ++i) GITER(2 * i, false);
  GITER(30, true);

  #undef GITER
  #undef STG
  #undef QUAD
  #undef VMW6
  #undef VMW3
  #undef LGK0
  #undef VMW0

  #pragma unroll
  for (int mm = 0; mm < 4; ++mm)
    #pragma unroll
    for (int n = 0; n < 4; ++n)
      #pragma unroll
      for (int r = 0; r < 4; ++r) {
        int row = bm + wm * 64 + mm * 16 + hi * 4 + r;
        int col = bn + wn * 64 + n * 16 + lo;
        C[(size_t)row * 2048 + col] = acc[mm][n][r];
      }
}

// ---- phase-split counted-vmcnt GEMM (2-phase, for Mfused prep) ----
template<int BN, int NBY, int NBX, int CBY, int CBX, int KLEN, int LDA, int OUT_BF16>
__global__ __launch_bounds__(512, 2)
void gemm_ps(const __bf16* __restrict__ A, const __bf16* __restrict__ BT,
             void* __restrict__ Cout, int az, int cz, int ldc) {
  constexpr int FN = BN / 64;
  constexpr int LB = (BN > 128) ? 2 : 1;
  constexpr int VC = 2 + LB;
  constexpr int BUFSZ = 16384 + 8192 * LB;
  constexpr int CGX = NBX / CBX;
  static_assert((NBY / CBY) * CGX == 8, "chunk grid must be 8 XCDs");
  __shared__ __align__(16) char smem[2 * BUFSZ];
  int tid = threadIdx.x;
  int w = tid >> 6, l = tid & 63, hi = l >> 4, lo = l & 15;
  int wm = w >> 2, wn = w & 3;
  int lin = blockIdx.x;
  int xcd = lin & 7, idx = lin >> 3;
  int cy = xcd / CGX, cx = xcd % CGX;
  int iby = idx / CBX, ibx = idx % CBX;
  int bm = (cy * CBY + iby) * 256;
  int bn = (cx * CBX + ibx) * BN;
  const char* Ab = (const char*)(A + (size_t)blockIdx.y * az) + (size_t)bm * LDA * 2;
  const char* Bb = (const char*)BT + (size_t)bn * KLEN * 2;

  int sw = (((lo & 1) << 2) + hi) ^ (lo >> 1);
  int base_a = (wm * 64 + (lo >> 1)) * 128 + sw * 16;
  int base_b = 16384 + (wn * (BN / 8) + (lo >> 1)) * 128 + sw * 16;

  int se_r[2], se_g[2];
  #pragma unroll
  for (int q = 0; q < 2; ++q) {
    int e = q * 512 + tid;
    int lr = e >> 3, sl = e & 7;
    int x = sl ^ (lr & 7);
    se_r[q] = lr * 2 + (x >> 2);
    se_g[q] = x & 3;
  }
  int dstoff[2] = { (0 * 512 + w * 64) * 16, (1 * 512 + w * 64) * 16 };

  f32x4 acc[8][FN];
  #pragma unroll
  for (int m = 0; m < 8; ++m)
    #pragma unroll
    for (int n = 0; n < FN; ++n) acc[m][n] = (f32x4){0.f, 0.f, 0.f, 0.f};

  #define STAGE(BUFI, K0) do {                                                   \
    char* As_ = smem + (BUFI) * BUFSZ;                                           \
    char* Bs_ = As_ + 16384;                                                     \
    _Pragma("unroll")                                                            \
    for (int q = 0; q < 2; ++q)                                                  \
      load_lds16(Ab + (size_t)se_r[q] * (LDA * 2) + (size_t)(K0) * 2 + se_g[q] * 16, \
                 As_ + dstoff[q]);                                               \
    _Pragma("unroll")                                                            \
    for (int q = 0; q < LB; ++q)                                                 \
      load_lds16(Bb + (size_t)se_r[q] * (KLEN * 2) + (size_t)(K0) * 2 + se_g[q] * 16, \
                 Bs_ + dstoff[q]);                                               \
  } while (0)

  #define WAITVC() do {                                                \
    if constexpr (VC == 4) asm volatile("s_waitcnt vmcnt(4)" ::: "memory"); \
    else                   asm volatile("s_waitcnt vmcnt(3)" ::: "memory"); \
  } while (0)

  constexpr int NT = KLEN / 32;
  STAGE(0, 0);
  STAGE(1, 32);
  WAITVC();
  wg_barrier();

  for (int t = 0; t < NT; ++t) {
    char* buf = smem + (t & 1) * BUFSZ;
    bf16x8 bfr[FN], afr[8];
    #pragma unroll
    for (int n = 0; n < FN; ++n) bfr[n] = *(const bf16x8*)(buf + base_b + n * 1024);
    #pragma unroll
    for (int m = 0; m < 8; ++m) afr[m] = *(const bf16x8*)(buf + base_a + m * 1024);
    __builtin_amdgcn_s_setprio(1);
    #pragma unroll
    for (int m = 0; m < 4; ++m)
      #pragma unroll
      for (int n = 0; n < FN; ++n)
        acc[m][n] = __builtin_amdgcn_mfma_f32_16x16x32_bf16(afr[m], bfr[n], acc[m][n], 0, 0, 0);
    __builtin_amdgcn_s_setprio(0);
    asm volatile("s_waitcnt lgkmcnt(0)" ::: "memory");
    wg_barrier();

    if (t + 2 < NT) STAGE(t & 1, (t + 2) * 32);
    __builtin_amdgcn_s_setprio(1);
    #pragma unroll
    for (int m = 4; m < 8; ++m)
      #pragma unroll
      for (int n = 0; n < FN; ++n)
        acc[m][n] = __builtin_amdgcn_mfma_f32_16x16x32_bf16(afr[m], bfr[n], acc[m][n], 0, 0, 0);
    __builtin_amdgcn_s_setprio(0);
    if (t + 2 < NT) { WAITVC(); }
    else            { asm volatile("s_waitcnt vmcnt(0)" ::: "memory"); }
    wg_barrier();
  }
  #undef STAGE
  #undef WAITVC

  #pragma unroll
  for (int m = 0; m < 8; ++m)
    #pragma unroll
    for (int n = 0; n < FN; ++n)
      #pragma unroll
      for (int r = 0; r < 4; ++r) {
        int row = bm + wm * 128 + m * 16 + hi * 4 + r;
        int col = bn + wn * (BN / 4) + n * 16 + lo;
        if (OUT_BF16)
          ((__bf16*)Cout)[(size_t)blockIdx.y * cz + (size_t)row * ldc + col] = (__bf16)acc[m][n][r];
        else
          ((float*)Cout)[(size_t)blockIdx.y * cz + (size_t)row * ldc + col] = acc[m][n][r];
      }
}

// ---- RoPE on Q,K columns of QKV (proven R14 body) ----
__global__ __launch_bounds__(256)
void rope_bf16(__bf16* __restrict__ QKV,
               const float* __restrict__ fc, const float* __restrict__ fs) {
  int idx = blockIdx.x * 256 + threadIdx.x;
  int pg = idx & 15;
  int h = (idx >> 4) & 15;
  int n = idx >> 8;
  int t = n & 1023;
  float4 c4 = *(const float4*)(fc + t * 64 + pg * 4);
  float4 s4 = *(const float4*)(fs + t * 64 + pg * 4);
  float c[4] = {c4.x, c4.y, c4.z, c4.w};
  float s[4] = {s4.x, s4.y, s4.z, s4.w};
  size_t ofs = (size_t)n * QKVW + h * 128 + pg * 8;
  bf16x8 q = *(bf16x8*)(QKV + ofs);
  bf16x8 k = *(bf16x8*)(QKV + 2048 + ofs);
  bf16x8 oq, ok;
  #pragma unroll
  for (int j = 0; j < 4; ++j) {
    float x = (float)q[2 * j], y = (float)q[2 * j + 1];
    oq[2 * j]     = (__bf16)(x * c[j] - y * s[j]);
    oq[2 * j + 1] = (__bf16)(x * s[j] + y * c[j]);
    float u = (float)k[2 * j], vv = (float)k[2 * j + 1];
    ok[2 * j]     = (__bf16)(u * c[j] - vv * s[j]);
    ok[2 * j + 1] = (__bf16)(u * s[j] + vv * c[j]);
  }
  *(bf16x8*)(QKV + ofs) = oq;
  *(bf16x8*)(QKV + 2048 + ofs) = ok;
}

// ---- 32x32 MFMA flash attention, causal, dbuf async staging ----
__global__ __launch_bounds__(256, 2)
void attn_mfma2(__bf16* __restrict__ QKV, const __bf16* __restrict__ VT) {
  __shared__ __align__(16) char smem[65536];
  int tid = threadIdx.x;
  int w = tid >> 6, l = tid & 63;
  int lo = l & 31, hv = l >> 5;
  int wgid = blockIdx.x;
  int xcd = wgid & 7, idx = wgid >> 3;
  int s = idx & 7, j = s >> 1, odd = s & 1, hi5 = idx >> 5;
  int base = hi5 ? 7 - j : j;
  int qt = odd ? 7 - base : base;
  int bh = xcd * 8 + (idx >> 3);
  int b = bh >> 4, h = bh & 15;
  int qb = qt * 128;
  int wq0 = qb + w * 32;
  int qrow = wq0 + lo;
  const __bf16* qp = QKV + (size_t)(b * 1024 + qrow) * QKVW + h * 128;
  bf16x8 qf[8];
  #pragma unroll
  for (int c = 0; c < 8; ++c) qf[c] = *(const bf16x8*)(qp + c * 16 + hv * 8);

  f32x16 o[4];
  #pragma unroll
  for (int n = 0; n < 4; ++n)
    #pragma unroll
    for (int r = 0; r < 16; ++r) o[n][r] = 0.f;
  float mrun = -1e30f, lrun = 0.f;
  const float SCL = 0.08838834764831845f * 1.4426950408889634f;
  int src0 = lo, src1 = 32 + lo;
  int nt = 2 * qt + 2;

  #define ASTAGE(BUF, KT) do {                                                   \
    _Pragma("unroll")                                                            \
    for (int i = 0; i < 4; ++i) {                                                \
      int e = i * 256 + tid;                                                     \
      int row = e >> 4, g = e & 15;                                              \
      int gs = g ^ (row & 7);                                                    \
      const char* src = (const char*)QKV +                                       \
          ((size_t)(b * 1024 + (KT) * 64 + row) * QKVW + 2048 + h * 128) * 2 + gs * 16; \
      load_lds16(src, smem + (BUF) * 16384 + (i * 256 + w * 64) * 16);           \
    }                                                                            \
    _Pragma("unroll")                                                            \
    for (int i = 0; i < 4; ++i) {                                                \
      int e = i * 256 + tid;                                                     \
      int row = e >> 3, g = e & 7;                                               \
      int gs = g ^ (row & 7);                                                    \
      const char* src = (const char*)VT +                                        \
          ((size_t)(bh * 128 + row) * 1024 + (KT) * 64) * 2 + gs * 16;           \
      load_lds16(src, smem + 32768 + (BUF) * 16384 + (i * 256 + w * 64) * 16);   \
    }                                                                            \
  } while (0)

  ASTAGE(0, 0);
  asm volatile("s_waitcnt vmcnt(0)" ::: "memory");
  wg_barrier();

  for (int kt = 0; kt < nt; ++kt) {
    int cur = kt & 1;
    if (kt + 1 < nt) ASTAGE(cur ^ 1, kt + 1);
    int k0 = kt * 64;
    char* Ks  = smem + cur * 16384;
    char* VTs = smem + 32768 + cur * 16384;

    if (k0 <= wq0 + 31) {
      f32x16 sT[2];
      #pragma unroll
      for (int kk = 0; kk < 2; ++kk) {
        #pragma unroll
        for (int r = 0; r < 16; ++r) sT[kk][r] = 0.f;
        #pragma unroll
        for (int c = 0; c < 8; ++c) {
          bf16x8 kf = *(const bf16x8*)(Ks + (kk * 32 + lo) * 256 + (((2 * c + hv) ^ (lo & 7)) * 16));
          sT[kk] = __builtin_amdgcn_mfma_f32_32x32x16_bf16(kf, qf[c], sT[kk], 0, 0, 0);
        }
      }
      bool diag = (k0 + 63 > wq0);
      float pv[2][16];
      #pragma unroll
      for (int kk = 0; kk < 2; ++kk)
        #pragma unroll
        for (int r = 0; r < 16; ++r) {
          float v = sT[kk][r] * SCL;
          if (diag) {
            int kg = k0 + kk * 32 + (r & 3) + 8 * (r >> 2) + 4 * hv;
            if (kg > qrow) v = -1e30f;
          }
          pv[kk][r] = v;
        }
      float mx = pv[0][0];
      #pragma unroll
      for (int kk = 0; kk < 2; ++kk)
        #pragma unroll
        for (int r = 0; r < 16; ++r) mx = fmaxf(mx, pv[kk][r]);
      mx = fmaxf(mx, __shfl_xor(mx, 32, 64));
      if (!__all(mx <= mrun + 8.f)) {
        float mnew = fmaxf(mrun, mx);
        float fac = exp2f(mrun - mnew);
        lrun *= fac;
        #pragma unroll
        for (int n = 0; n < 4; ++n)
          #pragma unroll
          for (int r = 0; r < 16; ++r) o[n][r] *= fac;
        mrun = mnew;
      }
      float rs = 0.f;
      #pragma unroll
      for (int kk = 0; kk < 2; ++kk)
        #pragma unroll
        for (int r = 0; r < 16; ++r) {
          float p = exp2f(pv[kk][r] - mrun);
          pv[kk][r] = p;
          rs += p;
        }
      rs += __shfl_xor(rs, 32, 64);
      lrun += rs;

      unsigned pk[2][4][2];
      #pragma unroll
      for (int kk = 0; kk < 2; ++kk)
        #pragma unroll
        for (int m = 0; m < 4; ++m)
          #pragma unroll
          for (int u = 0; u < 2; ++u)
            pk[kk][m][u] = pack2(pv[kk][m * 4 + 2 * u], pv[kk][m * 4 + 2 * u + 1]);

      #pragma unroll
      for (int kk = 0; kk < 2; ++kk) {
        #pragma unroll
        for (int s2 = 0; s2 < 2; ++s2) {
          unsigned a0 = __shfl(pk[kk][2 * s2][0], src0, 64);
          unsigned b0 = __shfl(pk[kk][2 * s2 + 1][0], src0, 64);
          unsigned a1 = __shfl(pk[kk][2 * s2][1], src0, 64);
          unsigned b1 = __shfl(pk[kk][2 * s2 + 1][1], src0, 64);
          unsigned a2 = __shfl(pk[kk][2 * s2][0], src1, 64);
          unsigned b2 = __shfl(pk[kk][2 * s2 + 1][0], src1, 64);
          unsigned a3 = __shfl(pk[kk][2 * s2][1], src1, 64);
          unsigned b3 = __shfl(pk[kk][2 * s2 + 1][1], src1, 64);
          union { unsigned u[4]; bf16x8 v; } pb;
          pb.u[0] = hv ? b0 : a0;
          pb.u[1] = hv ? b1 : a1;
          pb.u[2] = hv ? b2 : a2;
          pb.u[3] = hv ? b3 : a3;
          int ks16 = 2 * kk + s2;
          #pragma unroll
          for (int n = 0; n < 4; ++n) {
            bf16x8 vf = *(const bf16x8*)(VTs + (n * 32 + lo) * 128 +
                                         (((2 * ks16 + hv) ^ (lo & 7)) * 16));
            o[n] = __builtin_amdgcn_mfma_f32_32x32x16_bf16(vf, pb.v, o[n], 0, 0, 0);
          }
        }
      }
    }
    asm volatile("s_waitcnt vmcnt(0)" ::: "memory");
    wg_barrier();
  }
  #undef ASTAGE

  float inv = 1.f / lrun;
  __bf16* op = QKV + (size_t)(b * 1024 + qrow) * QKVW + h * 128;
  #pragma unroll
  for (int n = 0; n < 4; ++n)
    #pragma unroll
    for (int m4 = 0; m4 < 4; ++m4) {
      bf16x4 ov;
      #pragma unroll
      for (int jj = 0; jj < 4; ++jj) ov[jj] = (__bf16)(o[n][m4 * 4 + jj] * inv);
      *(bf16x4*)(op + n * 32 + 8 * m4 + 4 * hv) = ov;
    }
}

extern "C" void kernel_launch(void* const* d_in, const int* in_sizes, int n_in,
                              void* d_out, int out_size, void* d_ws, size_t ws_size,
                              hipStream_t stream) {
  const float* x    = (const float*)d_in[0];
  const float* fc   = (const float*)d_in[1];
  const float* fs   = (const float*)d_in[2];
  const float* wq   = (const float*)d_in[3];
  const float* wk   = (const float*)d_in[4];
  const float* wv   = (const float*)d_in[5];
  const float* wo   = (const float*)d_in[6];
  const float* wm   = (const float*)d_in[7];
  const float* beta = (const float*)d_in[8];

  char* wsb = (char*)d_ws;
  __bf16* xb      = (__bf16*)(wsb);
  __bf16* MTqkv   = (__bf16*)(wsb + 16777216L);
  __bf16* QKV     = (__bf16*)(wsb + 41943040L);
  __bf16* VTb     = (__bf16*)(wsb + 92274688L);
  double* s8      = (double*)(wsb + 109051904L);
  double* part    = (double*)(wsb + 109052160L);
  double* rs8     = (double*)(wsb + 109054208L);
  __bf16* MTwo    = (__bf16*)(wsb);
  __bf16* BTfused = (__bf16*)(wsb + 8388608L);
  __bf16* MTmixP  = MTqkv;

  dim3 blk(256);

  cast_scale<<<8448, blk, 0, stream>>>(x, xb, wq, wk, wv, wo, part);
  scale_fin<<<1, dim3(64), 0, stream>>>(part, s8, rs8);
  build_oct3<<<dim3(16384, 3), blk, 0, stream>>>(wq, wk, wv, s8, rs8, MTqkv);

  // QKV = xb @ [Mq|Mk|Mv]^T; V columns land directly transposed in VTb
  gemm_qkv8<<<512, dim3(512), 0, stream>>>(xb, MTqkv, QKV, VTb);

  // fold mixer into final weight (MoT + mixer built in one dispatch)
  build_wo_mix<<<20480, blk, 0, stream>>>(wo, s8 + 24, rs8 + 24, MTwo, wm, beta, MTmixP);
  gemm_ps<128, 8, 8, 2, 4, 1024, 2048, 1>
      <<<dim3(64, 2), dim3(512), 0, stream>>>(MTwo, MTmixP, BTfused, 1024, 1024, 2048);

  // RoPE on Q,K only (V no longer written to QKV)
  rope_bf16<<<4096, blk, 0, stream>>>(QKV, fc, fs);

  attn_mfma2<<<dim3(512), blk, 0, stream>>>(QKV, VTb);

  // out = attn_out @ Mfused (8-phase final GEMM)
  gemm_fin8<<<256, dim3(512), 0, stream>>>(QKV, BTfused, (float*)d_out);
}